// Round 12
// baseline (89940.173 us; speedup 1.0000x reference)
//
#include <hip/hip_runtime.h>
#include <stdint.h>
#include <math.h>

#define HID   1024
#define CHARD 512
#define NC    50257
#define TLEN  2048
#define NBLK  256           // persistent blocks (one per CU)
#define NTHR  512           // threads per persistent block (8 waves)
#define NGRP2 2048          // screen groups (one 25-row group per wave-slot)
#define GR    25
#define GRREG 6             // screen rows held in VGPRs per wave
#define GRLDS 19            // screen rows held in LDS per wave
#define NBH   1571          // fallback head blocks
#define SQ    4064.0f       // 127 / 0.03125
#define INVSQ (1.0f/4064.0f)
#define QERR  (0.5f/4064.0f)
#define CANDR 192

typedef unsigned long long ull;
typedef unsigned char u8;
typedef float f32x4 __attribute__((ext_vector_type(4)));

__device__ __forceinline__ unsigned ford(float f) {
    unsigned b = __float_as_uint(f);
    return (b & 0x80000000u) ? ~b : (b | 0x80000000u);
}
__device__ __forceinline__ float unford(unsigned u) {
    return __uint_as_float((u & 0x80000000u) ? (u & 0x7FFFFFFFu) : ~u);
}
__device__ __forceinline__ ull packkv(float v, unsigned j) {
    return ((ull)ford(v) << 32) | (ull)(0xFFFFFFFFu - j);
}
__device__ __forceinline__ ull umaxu(ull a, ull b) { return a > b ? a : b; }
__device__ __forceinline__ ull shflx_ull(ull v, int m) {
    unsigned lo = (unsigned)v, hi = (unsigned)(v >> 32);
    lo = __shfl_xor(lo, m);
    hi = __shfl_xor(hi, m);
    return ((ull)hi << 32) | lo;
}

#define ALOADF(p)    __hip_atomic_load((p), __ATOMIC_RELAXED, __HIP_MEMORY_SCOPE_AGENT)
#define ASTORE(p, v) __hip_atomic_store((p), (v), __ATOMIC_RELAXED, __HIP_MEMORY_SCOPE_AGENT)

// ====== init: hh[0]=inputs, c=0, zero flags + records + bm ======
__global__ __launch_bounds__(256) void k_init(const float* __restrict__ inputs,
                                              float* __restrict__ hh,
                                              float* __restrict__ c,
                                              unsigned* __restrict__ flags4,
                                              ull* __restrict__ recA,
                                              ull* __restrict__ recB,
                                              ull* __restrict__ bm)
{
    int g = blockIdx.x * 256 + threadIdx.x;
    if (g < HID) { hh[g] = inputs[g]; c[g] = 0.f; }
    if (g < NBLK + 16) flags4[g] = 0u;
    if (g < NBLK) { recA[g] = 0ull; recB[g] = 0ull; }
    if (g < NGRP2) bm[g] = 0ull;
}

// ================= quantize W_head -> biased uint8: round(w*SQ)+128 =================
__global__ __launch_bounds__(256) void k_quant(const float* __restrict__ W,
                                               u8* __restrict__ W8)
{
    size_t base = ((size_t)blockIdx.x * 256 + threadIdx.x) * 16;
    if (base >= (size_t)NC * HID) return;
    const float4* src = (const float4*)(W + base);
    uint out[4];
    #pragma unroll
    for (int g = 0; g < 4; ++g) {
        float4 w = src[g];
        int a0 = (__float2int_rn(w.x * SQ) + 128) & 255;
        int a1 = (__float2int_rn(w.y * SQ) + 128) & 255;
        int a2 = (__float2int_rn(w.z * SQ) + 128) & 255;
        int a3 = (__float2int_rn(w.w * SQ) + 128) & 255;
        out[g] = (uint)(a0 | (a1 << 8) | (a2 << 16) | (a3 << 24));
    }
    *(uint4*)(W8 + base) = make_uint4(out[0], out[1], out[2], out[3]);
}

// ================= exact fp32 dot of W_head row j with staged h =================
__device__ __forceinline__ float exact_logit(const float4* hs4,
                                             const float* __restrict__ W_head,
                                             const float* __restrict__ b_head,
                                             int j, int lane)
{
    const float4* wr = (const float4*)(W_head + (size_t)j * HID);
    float a = 0.f;
    #pragma unroll
    for (int m = 0; m < 4; ++m) {
        float4 w = wr[m * 64 + lane], v = hs4[m * 64 + lane];
        a = fmaf(w.x, v.x, a); a = fmaf(w.y, v.y, a);
        a = fmaf(w.z, v.z, a); a = fmaf(w.w, v.w, a);
    }
    #pragma unroll
    for (int off = 32; off > 0; off >>= 1) a += __shfl_xor(a, off);
    return a + b_head[j];
}

// ====== fallback exact resolve (rare: screened gap <= 2E) — r10-proven ======
__device__ unsigned resolve_fb(const float4* hs4, ull* bm, float* abuf,
                               const float* __restrict__ W_head,
                               const float* __restrict__ b_head,
                               float mtil, float E, ull* red8, int tid)
{
    __shared__ int s_cnt, s_gcnt;
    __shared__ int s_grps[32];
    __shared__ int s_rows[CANDR];
    const int wave = tid >> 6;
    const int lane = tid & 63;
    const float thresh = mtil - 2.0f * E;
    const ull pkth = ((ull)ford(thresh)) << 32;
    if (tid == 0) { s_cnt = 0; s_gcnt = 0; }
    __syncthreads();
    #pragma unroll
    for (int rep = 0; rep < NGRP2 / NTHR; ++rep) {
        const int i = tid + rep * NTHR;
        if (ALOADF(&bm[i]) >= pkth) {
            int p = atomicAdd(&s_gcnt, 1);
            if (p < 32) s_grps[p] = i;
        }
    }
    __syncthreads();
    const int ngr = s_gcnt;
    int ncr;
    if (ngr <= 32) {
        for (int gq = 0; gq < ngr; ++gq) {
            const int j = s_grps[gq] * GR + tid;
            if (tid < GR && j < NC) {
                if (ALOADF(&abuf[j]) >= thresh) {
                    int p = atomicAdd(&s_cnt, 1);
                    if (p < CANDR) s_rows[p] = j;
                }
            }
        }
        __syncthreads();
        ncr = s_cnt;
    } else ncr = CANDR + 1;

    ull best = 0ull;
    if (ncr <= CANDR) {
        for (int q = wave; q < ncr; q += 8) {
            const int j = s_rows[q];
            best = umaxu(best, packkv(exact_logit(hs4, W_head, b_head, j, lane),
                                      (unsigned)j));
        }
    } else {
        for (int i = wave; i < NGRP2; i += 8) {
            if (ALOADF(&bm[i]) >= pkth) {
                const int jb2 = i * GR;
                const int je = jb2 + GR < NC ? jb2 + GR : NC;
                for (int j = jb2; j < je; ++j)
                    if (ALOADF(&abuf[j]) >= thresh)
                        best = umaxu(best, packkv(exact_logit(hs4, W_head, b_head, j, lane),
                                                  (unsigned)j));
            }
        }
    }
    __syncthreads();
    if (lane == 0) red8[wave] = best;
    __syncthreads();
    best = red8[0];
    #pragma unroll
    for (int w = 1; w < 8; ++w) best = umaxu(best, red8[w]);
    unsigned idx = 0xFFFFFFFFu - (unsigned)(best & 0xFFFFFFFFull);
    return idx < NC ? idx : (NC - 1);
}

// ================= biased-uint8 16-element dot =================
__device__ __forceinline__ float dot16u(uint4 q, float4 h0, float4 h1,
                                        float4 h2, float4 h3)
{
    float a = 0.f;
    a = fmaf((float)(q.x & 255u), h0.x, a);
    a = fmaf((float)((q.x >> 8) & 255u), h0.y, a);
    a = fmaf((float)((q.x >> 16) & 255u), h0.z, a);
    a = fmaf((float)(q.x >> 24), h0.w, a);
    a = fmaf((float)(q.y & 255u), h1.x, a);
    a = fmaf((float)((q.y >> 8) & 255u), h1.y, a);
    a = fmaf((float)((q.y >> 16) & 255u), h1.z, a);
    a = fmaf((float)(q.y >> 24), h1.w, a);
    a = fmaf((float)(q.z & 255u), h2.x, a);
    a = fmaf((float)((q.z >> 8) & 255u), h2.y, a);
    a = fmaf((float)((q.z >> 16) & 255u), h2.z, a);
    a = fmaf((float)(q.z >> 24), h2.w, a);
    a = fmaf((float)(q.w & 255u), h3.x, a);
    a = fmaf((float)((q.w >> 8) & 255u), h3.y, a);
    a = fmaf((float)((q.w >> 16) & 255u), h3.z, a);
    a = fmaf((float)(q.w >> 24), h3.w, a);
    return a;
}

// ===== persistent kernel: resolve fused into barrier B (top2 records) =====
__global__ __launch_bounds__(NTHR, 1) void k_persist(
    const float* __restrict__ W_ih, const float* __restrict__ W_hh,
    const float* __restrict__ b_ih, const float* __restrict__ b_hh,
    const float* __restrict__ embed,
    const float* __restrict__ W_head, const float* __restrict__ b_head,
    const u8* __restrict__ W8,
    float* hh, float* abuf, ull* bm,
    float* __restrict__ chars_out, const int* __restrict__ startp,
    unsigned* flags4, ull* recA, ull* recB)
{
    __shared__ uint4  w8L[8][GRLDS][64];     // 152 KB
    __shared__ float4 hs4[HID / 4];          // 4 KB
    __shared__ float4 xs4[CHARD / 4];        // 2 KB
    __shared__ ull    red8[8];
    __shared__ float  sred[8], sred2[8];
    __shared__ ull    wtop[8], gt8[8];
    __shared__ float  wsec[8], gs8[8];

    const int b    = blockIdx.x;
    const int tid  = threadIdx.x;
    const int wave = tid >> 6;
    const int lane = tid & 63;
    const int rL   = b * 4 + wave;       // LSTM row for waves 0-3
    const int g    = b * 8 + wave;       // screen group
    const int jb   = g * GR;
    const u8* Wp   = W8 + (size_t)jb * HID;

    // ---- persistent W8 slice: rows 0..5 -> VGPRs, rows 6..24 -> LDS ----
    uint4 qb[GRREG];
    #pragma unroll
    for (int rr = 0; rr < GRREG; ++rr) {
        const int j = jb + rr;
        qb[rr] = (j < NC) ? ((const uint4*)(Wp + (size_t)rr * HID))[lane]
                          : make_uint4(0, 0, 0, 0);
    }
    #pragma unroll
    for (int rr = 0; rr < GRLDS; ++rr) {
        const int j = jb + GRREG + rr;
        w8L[wave][rr][lane] = (j < NC)
            ? ((const uint4*)(Wp + (size_t)(GRREG + rr) * HID))[lane]
            : make_uint4(0, 0, 0, 0);
    }

    float bsum[4] = {0.f, 0.f, 0.f, 0.f};
    if (wave < 4) {
        #pragma unroll
        for (int q = 0; q < 4; ++q) bsum[q] = b_ih[q * HID + rL] + b_hh[q * HID + rL];
    }
    float creg = 0.f;
    __syncthreads();

    // ---- stage h0 + Sh ----
    float Sh;
    {
        float sa = 0.f;
        if (tid < 256) {
            float4 hv = ((const float4*)hh)[tid];
            hs4[tid] = hv;
            sa = fabsf(hv.x) + fabsf(hv.y) + fabsf(hv.z) + fabsf(hv.w);
        }
        #pragma unroll
        for (int off = 32; off > 0; off >>= 1) sa += __shfl_xor(sa, off);
        if (lane == 0) sred[wave] = sa;
        __syncthreads();
        Sh = 0.f;
        #pragma unroll
        for (int w = 0; w < 8; ++w) Sh += sred[w];
    }

    unsigned bk = 0;
    ull   g_top = 0ull;
    float g_sec = -3.0e38f;

    for (int t = 0; t < TLEN; ++t) {
        // ---- resolve prev argmax: fast path from barrier-B top2, else fallback ----
        unsigned idx;
        if (t == 0) {
            idx = (unsigned)startp[0];
        } else {
            const float gv = unford((unsigned)(g_top >> 32));
            unsigned gidx = 0xFFFFu - ((unsigned)(g_top >> 16) & 0xFFFFu);
            if (gidx >= NC) gidx = NC - 1;
            const float E = QERR * Sh * 1.02f + 1e-4f;
            if (gv - 2.0f * E > g_sec) {
                idx = gidx;          // certified exact argmax
            } else {
                idx = resolve_fb(hs4, bm, abuf, W_head, b_head, gv, E, red8, tid);
            }
            if (b == 0 && tid == 0) chars_out[t - 1] = (float)idx;
        }
        if (tid < 128) xs4[tid] = ((const float4*)(embed + (size_t)idx * CHARD))[tid];
        __syncthreads();

        // ---- LSTM (waves 0-3, weights streamed from L2) ----
        if (wave < 4) {
            float acc[4];
            #pragma unroll
            for (int q = 0; q < 4; ++q) {
                const float4* wi = (const float4*)(W_ih + (size_t)(q * HID + rL) * CHARD);
                const float4* wh = (const float4*)(W_hh + (size_t)(q * HID + rL) * HID);
                float a = 0.f;
                #pragma unroll
                for (int m = 0; m < 2; ++m) {
                    float4 w = wi[m * 64 + lane], v = xs4[m * 64 + lane];
                    a = fmaf(w.x, v.x, a); a = fmaf(w.y, v.y, a);
                    a = fmaf(w.z, v.z, a); a = fmaf(w.w, v.w, a);
                }
                #pragma unroll
                for (int m = 0; m < 4; ++m) {
                    float4 w = wh[m * 64 + lane], v = hs4[m * 64 + lane];
                    a = fmaf(w.x, v.x, a); a = fmaf(w.y, v.y, a);
                    a = fmaf(w.z, v.z, a); a = fmaf(w.w, v.w, a);
                }
                acc[q] = a;
            }
            #pragma unroll
            for (int q = 0; q < 4; ++q) {
                #pragma unroll
                for (int off = 32; off > 0; off >>= 1) acc[q] += __shfl_xor(acc[q], off);
            }
            if (lane == 0) {
                float ig = 1.f / (1.f + expf(-(acc[0] + bsum[0])));
                float fg = 1.f / (1.f + expf(-(acc[1] + bsum[1])));
                float gg = tanhf(acc[2] + bsum[2]);
                float og = 1.f / (1.f + expf(-(acc[3] + bsum[3])));
                creg = fg * creg + ig * gg;
                ASTORE(&hh[(size_t)(t + 1) * HID + rL], og * tanhf(creg));
            }
        }

        // ---- barrier A: single-hop packed flags (h_{t+1} ready) ----
        ++bk;
        __syncthreads();
        if (tid == 0)
            ASTORE(&flags4[b], bk);
        if (tid < NBLK) {
            int guard = 0;
            while (ALOADF(&flags4[tid]) < bk) {
                __builtin_amdgcn_s_sleep(1);
                if (++guard > (1 << 24)) break;
            }
        }
        __syncthreads();

        // ---- stage h_{t+1}: Sh (abs-sum) + Hsum (plain sum) ----
        {
            float sa = 0.f, ss = 0.f;
            if (tid < 256) {
                float4 hv = ((const float4*)(hh + (size_t)(t + 1) * HID))[tid];
                hs4[tid] = hv;
                sa = fabsf(hv.x) + fabsf(hv.y) + fabsf(hv.z) + fabsf(hv.w);
                ss = hv.x + hv.y + hv.z + hv.w;
            }
            #pragma unroll
            for (int off = 32; off > 0; off >>= 1) {
                sa += __shfl_xor(sa, off);
                ss += __shfl_xor(ss, off);
            }
            if (lane == 0) { sred[wave] = sa; sred2[wave] = ss; }
        }
        __syncthreads();
        float Hsum = 0.f;
        Sh = 0.f;
        #pragma unroll
        for (int w = 0; w < 8; ++w) { Sh += sred[w]; Hsum += sred2[w]; }

        const float4 H0 = hs4[lane * 4 + 0];
        const float4 H1 = hs4[lane * 4 + 1];
        const float4 H2 = hs4[lane * 4 + 2];
        const float4 H3 = hs4[lane * 4 + 3];

        // ---- screen 25 rows; publish abuf + bm; build group top + second ----
        ull pmw = 0ull;
        float gsec = -3.0e38f;
        if (jb < NC) {
            float sv = -3.0e38f;      // lane r holds screened value of row r
            #pragma unroll
            for (int rr = 0; rr < GRREG; ++rr) {
                const int j = jb + rr;
                if (j < NC) {
                    float a = dot16u(qb[rr], H0, H1, H2, H3);
                    #pragma unroll
                    for (int off = 32; off > 0; off >>= 1) a += __shfl_xor(a, off);
                    const float v = (a - 128.f * Hsum) * INVSQ + b_head[j];
                    if (lane == rr) sv = v;
                    if (lane == 0) ASTORE(&abuf[j], v);
                    pmw = umaxu(pmw, packkv(v, (unsigned)j));
                }
            }
            #pragma unroll
            for (int rr = 0; rr < GRLDS; ++rr) {
                const int j = jb + GRREG + rr;
                if (j < NC) {
                    float a = dot16u(w8L[wave][rr][lane], H0, H1, H2, H3);
                    #pragma unroll
                    for (int off = 32; off > 0; off >>= 1) a += __shfl_xor(a, off);
                    const float v = (a - 128.f * Hsum) * INVSQ + b_head[j];
                    if (lane == GRREG + rr) sv = v;
                    if (lane == 0) ASTORE(&abuf[j], v);
                    pmw = umaxu(pmw, packkv(v, (unsigned)j));
                }
            }
            const int stop = (int)(0xFFFFFFFFu - (unsigned)(pmw & 0xFFFFFFFFull)) - jb;
            float s2 = (lane == stop) ? -3.0e38f : sv;
            #pragma unroll
            for (int off = 32; off > 0; off >>= 1) s2 = fmaxf(s2, __shfl_xor(s2, off));
            gsec = s2;
            if (lane == 0) ASTORE(&bm[g], pmw);
        }
        if (lane == 0) { wtop[wave] = pmw; wsec[wave] = gsec; }

        // ---- barrier B (fused resolve): publish block top2 record, poll+merge ----
        ++bk;
        __syncthreads();       // drains abuf/bm stores; wtop/wsec visible
        {
            // block-level top2 from 8 waves
            ull bt = 0ull; float bs = -3.0e38f;
            #pragma unroll
            for (int w = 0; w < 8; ++w) {
                ull tt = wtop[w]; float ssv = wsec[w];
                bs = fmaxf(bs, ssv);
                if (tt) {
                    if (bt) {
                        ull lo = bt < tt ? bt : tt;
                        bs = fmaxf(bs, unford((unsigned)(lo >> 32)));
                        bt = bt > tt ? bt : tt;
                    } else bt = tt;
                }
            }
            if (tid == 0) {
                ull ra;
                if (bt) {
                    unsigned idx32 = 0xFFFFFFFFu - (unsigned)(bt & 0xFFFFFFFFull);
                    unsigned inv16 = 0xFFFFu - (idx32 & 0xFFFFu);
                    ra = ((bt >> 32) << 32) | ((ull)inv16 << 16) | (ull)(bk & 0xFFFFu);
                } else {
                    ra = (ull)(bk & 0xFFFFu);
                }
                ASTORE(&recA[b], ra);
                ull rb = (((ull)ford(bs)) << 16) | (ull)(bk & 0xFFFFu);
                ASTORE(&recB[b], rb);
            }
            // poll all 256 records; merge global top2
            ull mt = 0ull; float msv = -3.0e38f;
            if (tid < NBLK) {
                ull rA = 0ull, rB = 0ull;
                int guard = 0;
                for (;;) {
                    rA = ALOADF(&recA[tid]);
                    rB = ALOADF(&recB[tid]);
                    if (((rA ^ (ull)bk) & 0xFFFFull) == 0 &&
                        ((rB ^ (ull)bk) & 0xFFFFull) == 0) break;
                    __builtin_amdgcn_s_sleep(1);
                    if (++guard > (1 << 24)) break;
                }
                if (rA >> 32) mt = rA & ~0xFFFFull;
                msv = unford((unsigned)(rB >> 16));
            }
            #pragma unroll
            for (int off = 32; off > 0; off >>= 1) {
                ull pt = shflx_ull(mt, off);
                float ps = __shfl_xor(msv, off);
                msv = fmaxf(msv, ps);
                if (pt) {
                    if (mt) {
                        ull lo = mt < pt ? mt : pt;
                        msv = fmaxf(msv, unford((unsigned)(lo >> 32)));
                        mt = mt > pt ? mt : pt;
                    } else mt = pt;
                }
            }
            if (lane == 0) { gt8[wave] = mt; gs8[wave] = msv; }
            __syncthreads();
            mt = 0ull; msv = -3.0e38f;
            #pragma unroll
            for (int w = 0; w < 8; ++w) {
                ull tt = gt8[w]; float ssv = gs8[w];
                msv = fmaxf(msv, ssv);
                if (tt) {
                    if (mt) {
                        ull lo = mt < tt ? mt : tt;
                        msv = fmaxf(msv, unford((unsigned)(lo >> 32)));
                        mt = mt > tt ? mt : tt;
                    } else mt = tt;
                }
            }
            g_top = mt;
            g_sec = msv;
        }
    }

    // ---- final char (block 0 only) ----
    if (b == 0) {
        const float gv = unford((unsigned)(g_top >> 32));
        unsigned gidx = 0xFFFFu - ((unsigned)(g_top >> 16) & 0xFFFFu);
        if (gidx >= NC) gidx = NC - 1;
        const float E = QERR * Sh * 1.02f + 1e-4f;
        unsigned idx = (gv - 2.0f * E > g_sec) ? gidx
                     : resolve_fb(hs4, bm, abuf, W_head, b_head, gv, E, red8, tid);
        if (tid == 0) chars_out[TLEN - 1] = (float)idx;
    }
}

// ================= phase B: logits[t][j] = W_head[j]·h_t + b_head[j] =================
#define GJ 64
#define GT 128
#define GK 16
__global__ __launch_bounds__(256) void k_gemm(const float* __restrict__ W_head,
                                              const float* __restrict__ b_head,
                                              const float* __restrict__ hh,
                                              float* __restrict__ logits)
{
    __shared__ float Ws[GK][GJ + 4];
    __shared__ float Hs[GK][GT + 1];

    const int tid = threadIdx.x;
    const int j0 = blockIdx.x * GJ;
    const int t0 = blockIdx.y * GT;
    const int tj = tid & 15;
    const int tt = tid >> 4;

    const int wlj = tid >> 2;
    const int wlk = (tid & 3) * 4;
    const int hlt = tid >> 1;
    const int hlk = (tid & 1) * 8;
    const float* Wrow = W_head + (size_t)(j0 + wlj) * HID;
    const bool wvalid = (j0 + wlj) < NC;

    float acc[8][4];
    #pragma unroll
    for (int bb = 0; bb < 8; ++bb)
        #pragma unroll
        for (int a = 0; a < 4; ++a) acc[bb][a] = 0.f;

    for (int k0 = 0; k0 < HID; k0 += GK) {
        __syncthreads();
        float4 wv = wvalid ? *(const float4*)(Wrow + k0 + wlk) : make_float4(0, 0, 0, 0);
        Ws[wlk + 0][wlj] = wv.x; Ws[wlk + 1][wlj] = wv.y;
        Ws[wlk + 2][wlj] = wv.z; Ws[wlk + 3][wlj] = wv.w;
        const float* hp = hh + (size_t)(t0 + hlt + 1) * HID + k0 + hlk;
        float4 a0 = *(const float4*)hp;
        float4 a1 = *(const float4*)(hp + 4);
        Hs[hlk + 0][hlt] = a0.x; Hs[hlk + 1][hlt] = a0.y;
        Hs[hlk + 2][hlt] = a0.z; Hs[hlk + 3][hlt] = a0.w;
        Hs[hlk + 4][hlt] = a1.x; Hs[hlk + 5][hlt] = a1.y;
        Hs[hlk + 6][hlt] = a1.z; Hs[hlk + 7][hlt] = a1.w;
        __syncthreads();
        #pragma unroll
        for (int kk = 0; kk < GK; ++kk) {
            float4 w4 = *(const float4*)&Ws[kk][tj * 4];
            float hvv[8];
            #pragma unroll
            for (int bb = 0; bb < 8; ++bb) hvv[bb] = Hs[kk][tt + 16 * bb];
            #pragma unroll
            for (int bb = 0; bb < 8; ++bb) {
                acc[bb][0] = fmaf(w4.x, hvv[bb], acc[bb][0]);
                acc[bb][1] = fmaf(w4.y, hvv[bb], acc[bb][1]);
                acc[bb][2] = fmaf(w4.z, hvv[bb], acc[bb][2]);
                acc[bb][3] = fmaf(w4.w, hvv[bb], acc[bb][3]);
            }
        }
    }

    const int j = j0 + tj * 4;
    float b0 = (j + 0 < NC) ? b_head[j + 0] : 0.f;
    float b1 = (j + 1 < NC) ? b_head[j + 1] : 0.f;
    float b2 = (j + 2 < NC) ? b_head[j + 2] : 0.f;
    float b3 = (j + 3 < NC) ? b_head[j + 3] : 0.f;
    #pragma unroll
    for (int bb = 0; bb < 8; ++bb) {
        const int t = t0 + tt + 16 * bb;
        float* dst = logits + (size_t)t * NC + j;
        if (j + 3 < NC) {
            f32x4 o = { acc[bb][0] + b0, acc[bb][1] + b1,
                        acc[bb][2] + b2, acc[bb][3] + b3 };
            __builtin_nontemporal_store(o, (f32x4*)dst);
        } else {
            if (j + 0 < NC) dst[0] = acc[bb][0] + b0;
            if (j + 1 < NC) dst[1] = acc[bb][1] + b1;
            if (j + 2 < NC) dst[2] = acc[bb][2] + b2;
        }
    }
}

// ======================================================================
// ===================== fallback (round-1, proven) =====================
// ======================================================================
__global__ __launch_bounds__(256) void k_init_fb(const float* __restrict__ inputs,
                                                 const int* __restrict__ startp,
                                                 float* __restrict__ h0,
                                                 float* __restrict__ c,
                                                 ull* __restrict__ blockmax)
{
    int tid = blockIdx.x * 256 + threadIdx.x;
    if (tid < NBH) blockmax[tid] = (tid == 0) ? packkv(3.0e38f, (unsigned)startp[0]) : 0ull;
    if (tid < HID) { h0[tid] = inputs[tid]; c[tid] = 0.f; }
}

__global__ __launch_bounds__(256) void k_lstm_fb(const float* __restrict__ W_ih,
                                                 const float* __restrict__ W_hh,
                                                 const float* __restrict__ b_ih,
                                                 const float* __restrict__ b_hh,
                                                 const float* __restrict__ embed,
                                                 const ull* __restrict__ blockmax,
                                                 const float* __restrict__ h_in,
                                                 float* __restrict__ h_out,
                                                 float* __restrict__ c,
                                                 float* __restrict__ chars_out,
                                                 int t)
{
    __shared__ float4 xs4[CHARD / 4];
    __shared__ float4 hs4[HID / 4];
    __shared__ ull    red[256];
    const int tid = threadIdx.x;
    ull pm = 0ull;
    for (int i = tid; i < NBH; i += 256) pm = umaxu(pm, blockmax[i]);
    red[tid] = pm;
    __syncthreads();
    for (int s = 128; s > 0; s >>= 1) {
        if (tid < s) red[tid] = umaxu(red[tid], red[tid + s]);
        __syncthreads();
    }
    const unsigned idx = 0xFFFFFFFFu - (unsigned)(red[0] & 0xFFFFFFFFull);
    if (t > 0 && blockIdx.x == 0 && tid == 0) chars_out[t - 1] = (float)idx;
    const float4* ex = (const float4*)(embed + (size_t)idx * CHARD);
    if (tid < 128) xs4[tid] = ex[tid];
    hs4[tid] = ((const float4*)h_in)[tid];
    __syncthreads();
    const int wave = tid >> 6, lane = tid & 63;
    const int r = blockIdx.x * 4 + wave;
    float acc[4];
    #pragma unroll
    for (int q = 0; q < 4; ++q) {
        const float4* wi = (const float4*)(W_ih + (size_t)(q * HID + r) * CHARD);
        const float4* wh = (const float4*)(W_hh + (size_t)(q * HID + r) * HID);
        float a = 0.f;
        #pragma unroll
        for (int m = 0; m < 2; ++m) {
            float4 w = wi[m * 64 + lane], v = xs4[m * 64 + lane];
            a = fmaf(w.x, v.x, a); a = fmaf(w.y, v.y, a);
            a = fmaf(w.z, v.z, a); a = fmaf(w.w, v.w, a);
        }
        #pragma unroll
        for (int m = 0; m < 4; ++m) {
            float4 w = wh[m * 64 + lane], v = hs4[m * 64 + lane];
            a = fmaf(w.x, v.x, a); a = fmaf(w.y, v.y, a);
            a = fmaf(w.z, v.z, a); a = fmaf(w.w, v.w, a);
        }
        acc[q] = a;
    }
    #pragma unroll
    for (int q = 0; q < 4; ++q)
        #pragma unroll
        for (int off = 32; off > 0; off >>= 1) acc[q] += __shfl_xor(acc[q], off);
    if (lane == 0) {
        float zi = acc[0] + b_ih[r]           + b_hh[r];
        float zf = acc[1] + b_ih[HID + r]     + b_hh[HID + r];
        float zg = acc[2] + b_ih[2 * HID + r] + b_hh[2 * HID + r];
        float zo = acc[3] + b_ih[3 * HID + r] + b_hh[3 * HID + r];
        float ig = 1.f / (1.f + expf(-zi));
        float fg = 1.f / (1.f + expf(-zf));
        float gg = tanhf(zg);
        float og = 1.f / (1.f + expf(-zo));
        float cn = fg * c[r] + ig * gg;
        c[r] = cn;
        h_out[r] = og * tanhf(cn);
    }
}

__global__ __launch_bounds__(256) void k_head_fb(const float* __restrict__ W_head,
                                                 const float* __restrict__ b_head,
                                                 const float* __restrict__ h_in,
                                                 float* __restrict__ logits,
                                                 ull* __restrict__ blockmax)
{
    __shared__ float4 hs4[HID / 4];
    __shared__ ull    wmax[4];
    const int tid = threadIdx.x;
    hs4[tid] = ((const float4*)h_in)[tid];
    __syncthreads();
    const int wave = tid >> 6, lane = tid & 63;
    const int base = blockIdx.x * 32 + wave * 8;
    ull pm = 0ull;
    #pragma unroll
    for (int rep = 0; rep < 8; ++rep) {
        const int j = base + rep;
        if (j < NC) {
            const float4* w = (const float4*)(W_head + (size_t)j * HID);
            float a = 0.f;
            #pragma unroll
            for (int m = 0; m < 4; ++m) {
                float4 ww = w[m * 64 + lane], v = hs4[m * 64 + lane];
                a = fmaf(ww.x, v.x, a); a = fmaf(ww.y, v.y, a);
                a = fmaf(ww.z, v.z, a); a = fmaf(ww.w, v.w, a);
            }
            #pragma unroll
            for (int off = 32; off > 0; off >>= 1) a += __shfl_xor(a, off);
            const float v = a + b_head[j];
            if (lane == 0) __builtin_nontemporal_store(v, &logits[j]);
            pm = umaxu(pm, packkv(v, (unsigned)j));
        }
    }
    if (lane == 0) wmax[wave] = pm;
    __syncthreads();
    if (tid == 0)
        blockmax[blockIdx.x] = umaxu(umaxu(wmax[0], wmax[1]), umaxu(wmax[2], wmax[3]));
}

__global__ __launch_bounds__(256) void k_final_fb(const ull* __restrict__ blockmax,
                                                  float* __restrict__ chars_out)
{
    __shared__ ull red[256];
    const int tid = threadIdx.x;
    ull pm = 0ull;
    for (int i = tid; i < NBH; i += 256) pm = umaxu(pm, blockmax[i]);
    red[tid] = pm;
    __syncthreads();
    for (int s = 128; s > 0; s >>= 1) {
        if (tid < s) red[tid] = umaxu(red[tid], red[tid + s]);
        __syncthreads();
    }
    if (tid == 0)
        chars_out[TLEN - 1] = (float)(0xFFFFFFFFu - (unsigned)(red[0] & 0xFFFFFFFFull));
}

// ======================================================================
extern "C" void kernel_launch(void* const* d_in, const int* in_sizes, int n_in,
                              void* d_out, int out_size, void* d_ws, size_t ws_size,
                              hipStream_t stream)
{
    const float* inputs = (const float*)d_in[0];
    const float* embed  = (const float*)d_in[1];
    const float* W_ih   = (const float*)d_in[2];
    const float* W_hh   = (const float*)d_in[3];
    const float* b_ih   = (const float*)d_in[4];
    const float* b_hh   = (const float*)d_in[5];
    const float* W_head = (const float*)d_in[6];
    const float* b_head = (const float*)d_in[7];
    const int*   startp = (const int*)d_in[9];

    float* out        = (float*)d_out;
    float* chars_out  = out;          // [2048]
    float* logits_out = out + TLEN;   // [2048 * 50257]

    char* ws = (char*)d_ws;
    const size_t off_hh    = 0;
    const size_t off_c     = off_hh + (size_t)(TLEN + 1) * HID * 4;
    const size_t off_ab    = off_c + (size_t)HID * 4;
    const size_t off_bm    = (off_ab + (size_t)NC * 4 + 15) & ~(size_t)15;
    const size_t off_fl    = (off_bm + (size_t)NGRP2 * 8 + 63) & ~(size_t)63;
    const size_t off_ra    = (off_fl + (size_t)(NBLK + 16) * 4 + 63) & ~(size_t)63;
    const size_t off_rb    = off_ra + (size_t)NBLK * 8;
    const size_t off_w8    = (off_rb + (size_t)NBLK * 8 + 15) & ~(size_t)15;
    const size_t need      = off_w8 + (size_t)NC * HID;

    if (ws_size >= need) {
        float*    hh     = (float*)(ws + off_hh);
        float*    c      = (float*)(ws + off_c);
        float*    abuf   = (float*)(ws + off_ab);
        ull*      bm     = (ull*)(ws + off_bm);
        unsigned* flags4 = (unsigned*)(ws + off_fl);
        ull*      recA   = (ull*)(ws + off_ra);
        ull*      recB   = (ull*)(ws + off_rb);
        u8*       W8     = (u8*)(ws + off_w8);

        hipLaunchKernelGGL(k_init, dim3(8), dim3(256), 0, stream,
                           inputs, hh, c, flags4, recA, recB, bm);
        hipLaunchKernelGGL(k_quant, dim3((NC * HID / 16 + 255) / 256), dim3(256), 0,
                           stream, W_head, W8);
        hipLaunchKernelGGL(k_persist, dim3(NBLK), dim3(NTHR), 0, stream,
                           W_ih, W_hh, b_ih, b_hh, embed, W_head, b_head, W8,
                           hh, abuf, bm, chars_out, startp, flags4, recA, recB);
        hipLaunchKernelGGL(k_gemm, dim3((NC + GJ - 1) / GJ, TLEN / GT), dim3(256), 0,
                           stream, W_head, b_head, hh, logits_out);
    } else {
        // fallback: round-1 path (needs ~25 KB ws)
        float* h0 = (float*)(ws);
        float* h1 = (float*)(ws + 4096);
        float* c  = (float*)(ws + 8192);
        ull* blockmax = (ull*)(ws + 12288);
        hipLaunchKernelGGL(k_init_fb, dim3(7), dim3(256), 0, stream,
                           inputs, startp, h0, c, blockmax);
        for (int t = 0; t < TLEN; ++t) {
            const float* hin = (t & 1) ? h1 : h0;
            float*       hout = (t & 1) ? h0 : h1;
            hipLaunchKernelGGL(k_lstm_fb, dim3(256), dim3(256), 0, stream,
                               W_ih, W_hh, b_ih, b_hh, embed, blockmax,
                               hin, hout, c, chars_out, t);
            hipLaunchKernelGGL(k_head_fb, dim3(NBH), dim3(256), 0, stream,
                               W_head, b_head, hout,
                               logits_out + (size_t)t * NC, blockmax);
        }
        hipLaunchKernelGGL(k_final_fb, dim3(1), dim3(256), 0, stream, blockmax, chars_out);
    }
}

// Round 13
// 52594.104 us; speedup vs baseline: 1.7101x; 1.7101x over previous
//
#include <hip/hip_runtime.h>
#include <stdint.h>
#include <math.h>

#define HID   1024
#define CHARD 512
#define NC    50257
#define TLEN  2048
#define NBLK  256           // persistent blocks (one per CU)
#define NTHR  512           // threads per persistent block (8 waves)
#define NGRP2 2048          // screen groups (one 25-row group per wave-slot)
#define GR    25
#define GRREG 6             // screen rows held in VGPRs per wave
#define GRLDS 19            // screen rows held in LDS per wave
#define NBH   1571          // fallback head blocks
#define SQ    4064.0f       // 127 / 0.03125
#define INVSQ (1.0f/4064.0f)
#define QERR  (0.5f/4064.0f)
#define CANDR 192

typedef unsigned long long ull;
typedef unsigned char u8;
typedef float f32x4 __attribute__((ext_vector_type(4)));

__device__ __forceinline__ unsigned ford(float f) {
    unsigned b = __float_as_uint(f);
    return (b & 0x80000000u) ? ~b : (b | 0x80000000u);
}
__device__ __forceinline__ float unford(unsigned u) {
    return __uint_as_float((u & 0x80000000u) ? (u & 0x7FFFFFFFu) : ~u);
}
__device__ __forceinline__ ull packkv(float v, unsigned j) {
    return ((ull)ford(v) << 32) | (ull)(0xFFFFFFFFu - j);
}
__device__ __forceinline__ unsigned ceil16(float v) {   // 16-bit ford, rounded UP
    unsigned u = ford(v);
    return (u >> 16) + ((u & 0xFFFFu) ? 1u : 0u);
}
__device__ __forceinline__ ull umaxu(ull a, ull b) { return a > b ? a : b; }
__device__ __forceinline__ ull shflx_ull(ull v, int m) {
    unsigned lo = (unsigned)v, hi = (unsigned)(v >> 32);
    lo = __shfl_xor(lo, m);
    hi = __shfl_xor(hi, m);
    return ((ull)hi << 32) | lo;
}

#define ALOADF(p)    __hip_atomic_load((p), __ATOMIC_RELAXED, __HIP_MEMORY_SCOPE_AGENT)
#define ASTORE(p, v) __hip_atomic_store((p), (v), __ATOMIC_RELAXED, __HIP_MEMORY_SCOPE_AGENT)

// ====== init: hh[0]=inputs, c=0, zero flags/records/bm4/abuf16 ======
__global__ __launch_bounds__(256) void k_init(const float* __restrict__ inputs,
                                              float* __restrict__ hh,
                                              float* __restrict__ c,
                                              unsigned* __restrict__ flags4,
                                              ull* __restrict__ recA,
                                              unsigned* __restrict__ bm4,
                                              unsigned* __restrict__ abuf16)
{
    int g = blockIdx.x * 256 + threadIdx.x;
    if (g < HID) { hh[g] = inputs[g]; c[g] = 0.f; }
    if (g < NBLK + 16) flags4[g] = 0u;
    if (g < NBLK) recA[g] = 0ull;
    if (g < NGRP2) bm4[g] = 0u;
    for (int i = g; i < NC; i += 2048) abuf16[i] = 0u;
}

// ================= quantize W_head -> biased uint8: round(w*SQ)+128 =================
__global__ __launch_bounds__(256) void k_quant(const float* __restrict__ W,
                                               u8* __restrict__ W8)
{
    size_t base = ((size_t)blockIdx.x * 256 + threadIdx.x) * 16;
    if (base >= (size_t)NC * HID) return;
    const float4* src = (const float4*)(W + base);
    uint out[4];
    #pragma unroll
    for (int g = 0; g < 4; ++g) {
        float4 w = src[g];
        int a0 = (__float2int_rn(w.x * SQ) + 128) & 255;
        int a1 = (__float2int_rn(w.y * SQ) + 128) & 255;
        int a2 = (__float2int_rn(w.z * SQ) + 128) & 255;
        int a3 = (__float2int_rn(w.w * SQ) + 128) & 255;
        out[g] = (uint)(a0 | (a1 << 8) | (a2 << 16) | (a3 << 24));
    }
    *(uint4*)(W8 + base) = make_uint4(out[0], out[1], out[2], out[3]);
}

// ================= exact fp32 dot of W_head row j with staged h =================
__device__ __forceinline__ float exact_logit(const float4* hs4,
                                             const float* __restrict__ W_head,
                                             const float* __restrict__ b_head,
                                             int j, int lane)
{
    const float4* wr = (const float4*)(W_head + (size_t)j * HID);
    float a = 0.f;
    #pragma unroll
    for (int m = 0; m < 4; ++m) {
        float4 w = wr[m * 64 + lane], v = hs4[m * 64 + lane];
        a = fmaf(w.x, v.x, a); a = fmaf(w.y, v.y, a);
        a = fmaf(w.z, v.z, a); a = fmaf(w.w, v.w, a);
    }
    #pragma unroll
    for (int off = 32; off > 0; off >>= 1) a += __shfl_xor(a, off);
    return a + b_head[j];
}

// ================= biased-uint8 16-element dot =================
__device__ __forceinline__ float dot16u(uint4 q, float4 h0, float4 h1,
                                        float4 h2, float4 h3)
{
    float a = 0.f;
    a = fmaf((float)(q.x & 255u), h0.x, a);
    a = fmaf((float)((q.x >> 8) & 255u), h0.y, a);
    a = fmaf((float)((q.x >> 16) & 255u), h0.z, a);
    a = fmaf((float)(q.x >> 24), h0.w, a);
    a = fmaf((float)(q.y & 255u), h1.x, a);
    a = fmaf((float)((q.y >> 8) & 255u), h1.y, a);
    a = fmaf((float)((q.y >> 16) & 255u), h1.z, a);
    a = fmaf((float)(q.y >> 24), h1.w, a);
    a = fmaf((float)(q.z & 255u), h2.x, a);
    a = fmaf((float)((q.z >> 8) & 255u), h2.y, a);
    a = fmaf((float)((q.z >> 16) & 255u), h2.z, a);
    a = fmaf((float)(q.z >> 24), h2.w, a);
    a = fmaf((float)(q.w & 255u), h3.x, a);
    a = fmaf((float)((q.w >> 8) & 255u), h3.y, a);
    a = fmaf((float)((q.w >> 16) & 255u), h3.z, a);
    a = fmaf((float)(q.w >> 24), h3.w, a);
    return a;
}

// ===== persistent kernel: r10 structure + gen-tagged 4B bm/abuf + record-fused barrier B =====
__global__ __launch_bounds__(NTHR, 1) void k_persist(
    const float* __restrict__ W_ih, const float* __restrict__ W_hh,
    const float* __restrict__ b_ih, const float* __restrict__ b_hh,
    const float* __restrict__ embed,
    const float* __restrict__ W_head, const float* __restrict__ b_head,
    const u8* __restrict__ W8,
    float* hh, unsigned* abuf16, unsigned* bm4,
    float* __restrict__ chars_out, const int* __restrict__ startp,
    unsigned* flags4, ull* recA)
{
    __shared__ uint4  w8L[8][GRLDS][64];     // 152 KB
    __shared__ float4 hs4[HID / 4];          // 4 KB
    __shared__ float4 xs4[CHARD / 4];        // 2 KB
    __shared__ ull    red8[8];
    __shared__ ull    wtop[8], gt8[8];
    __shared__ float  sred[8], sred2[8];
    __shared__ int    s_cnt, s_gcnt;
    __shared__ int    s_grps[32];
    __shared__ int    s_rows[CANDR];

    const int b    = blockIdx.x;
    const int tid  = threadIdx.x;
    const int wave = tid >> 6;
    const int lane = tid & 63;
    const int rL   = b * 4 + wave;       // LSTM row for waves 0-3
    const int g    = b * 8 + wave;       // screen group
    const int jb   = g * GR;
    const u8* Wp   = W8 + (size_t)jb * HID;

    // ---- persistent W8 slice: rows 0..5 -> VGPRs, rows 6..24 -> LDS ----
    uint4 qb[GRREG];
    #pragma unroll
    for (int rr = 0; rr < GRREG; ++rr) {
        const int j = jb + rr;
        qb[rr] = (j < NC) ? ((const uint4*)(Wp + (size_t)rr * HID))[lane]
                          : make_uint4(0, 0, 0, 0);
    }
    #pragma unroll
    for (int rr = 0; rr < GRLDS; ++rr) {
        const int j = jb + GRREG + rr;
        w8L[wave][rr][lane] = (j < NC)
            ? ((const uint4*)(Wp + (size_t)(GRREG + rr) * HID))[lane]
            : make_uint4(0, 0, 0, 0);
    }

    float bsum[4] = {0.f, 0.f, 0.f, 0.f};
    if (wave < 4) {
        #pragma unroll
        for (int q = 0; q < 4; ++q) bsum[q] = b_ih[q * HID + rL] + b_hh[q * HID + rL];
    }
    float creg = 0.f;
    __syncthreads();

    // ---- stage h0 ----
    if (tid < 256) hs4[tid] = ((const float4*)hh)[tid];
    __syncthreads();

    float Sh = 0.f;          // Sh of the h that produced current bm/abuf
    ull   g_top = 0ull;      // global screened top record (value32|invIdx16|0s)

    for (int t = 0; t < TLEN; ++t) {
        // ======== resolve prev argmax (exact, r10 semantics) ========
        unsigned idx;
        if (t == 0) {
            idx = (unsigned)startp[0];
        } else {
            const unsigned gen = (unsigned)t & 0xFFFFu;
            const float mtil = unford((unsigned)(g_top >> 32));
            const float E = QERR * Sh * 1.02f + 1e-4f;
            const float thresh = mtil - 2.0f * E;
            const unsigned th16 = ford(thresh) >> 16;
            if (tid == 0) { s_cnt = 0; s_gcnt = 0; }
            __syncthreads();

            // pass2a: one uint4 load covers 4 groups
            {
                uint4 bv = ((const uint4*)bm4)[tid];
                #pragma unroll
                for (int k = 0; k < 4; ++k) {
                    unsigned v = (&bv.x)[k];
                    if ((v & 0xFFFFu) == gen && (v >> 16) >= th16) {
                        int p = atomicAdd(&s_gcnt, 1);
                        if (p < 32) s_grps[p] = tid * 4 + k;
                    }
                }
            }
            __syncthreads();
            const int ngr = s_gcnt;
            int ncr;
            if (ngr <= 32) {
                for (int gq = wave; gq < ngr; gq += 8) {
                    if (lane < GR) {
                        const int j = s_grps[gq] * GR + lane;
                        if (j < NC) {
                            unsigned a = ALOADF(&abuf16[j]);
                            if ((a & 0xFFFFu) == gen && (a >> 16) >= th16) {
                                int p = atomicAdd(&s_cnt, 1);
                                if (p < CANDR) s_rows[p] = j;
                            }
                        }
                    }
                }
                __syncthreads();
                ncr = s_cnt;
            } else ncr = CANDR + 1;

            ull best = 0ull;
            if (ncr <= CANDR) {
                for (int q = wave; q < ncr; q += 8) {
                    const int j = s_rows[q];
                    best = umaxu(best, packkv(exact_logit(hs4, W_head, b_head, j, lane),
                                              (unsigned)j));
                }
            } else {
                // pathological overflow: exhaustive gen-checked scan
                for (int i = wave; i < NGRP2; i += 8) {
                    unsigned v = ALOADF(&bm4[i]);
                    if ((v & 0xFFFFu) == gen && (v >> 16) >= th16) {
                        const int j0 = i * GR;
                        unsigned a = 0u;
                        bool c = false;
                        if (lane < GR && j0 + lane < NC) {
                            a = ALOADF(&abuf16[j0 + lane]);
                            c = ((a & 0xFFFFu) == gen && (a >> 16) >= th16);
                        }
                        ull cnd = __ballot(c);
                        while (cnd) {
                            const int s = __builtin_ctzll(cnd);
                            cnd &= cnd - 1;
                            const int j = j0 + s;
                            best = umaxu(best, packkv(exact_logit(hs4, W_head, b_head, j, lane),
                                                      (unsigned)j));
                        }
                    }
                }
            }
            __syncthreads();
            if (lane == 0) red8[wave] = best;
            __syncthreads();
            best = red8[0];
            #pragma unroll
            for (int w = 1; w < 8; ++w) best = umaxu(best, red8[w]);
            idx = 0xFFFFFFFFu - (unsigned)(best & 0xFFFFFFFFull);
            if (idx >= NC) idx = NC - 1;
            if (b == 0 && tid == 0) chars_out[t - 1] = (float)idx;
        }
        if (tid < 128) xs4[tid] = ((const float4*)(embed + (size_t)idx * CHARD))[tid];
        __syncthreads();

        // ======== LSTM (waves 0-3, weights streamed from L2) ========
        if (wave < 4) {
            float acc[4];
            #pragma unroll
            for (int q = 0; q < 4; ++q) {
                const float4* wi = (const float4*)(W_ih + (size_t)(q * HID + rL) * CHARD);
                const float4* wh = (const float4*)(W_hh + (size_t)(q * HID + rL) * HID);
                float a = 0.f;
                #pragma unroll
                for (int m = 0; m < 2; ++m) {
                    float4 w = wi[m * 64 + lane], v = xs4[m * 64 + lane];
                    a = fmaf(w.x, v.x, a); a = fmaf(w.y, v.y, a);
                    a = fmaf(w.z, v.z, a); a = fmaf(w.w, v.w, a);
                }
                #pragma unroll
                for (int m = 0; m < 4; ++m) {
                    float4 w = wh[m * 64 + lane], v = hs4[m * 64 + lane];
                    a = fmaf(w.x, v.x, a); a = fmaf(w.y, v.y, a);
                    a = fmaf(w.z, v.z, a); a = fmaf(w.w, v.w, a);
                }
                acc[q] = a;
            }
            #pragma unroll
            for (int q = 0; q < 4; ++q) {
                #pragma unroll
                for (int off = 32; off > 0; off >>= 1) acc[q] += __shfl_xor(acc[q], off);
            }
            if (lane == 0) {
                float ig = 1.f / (1.f + expf(-(acc[0] + bsum[0])));
                float fg = 1.f / (1.f + expf(-(acc[1] + bsum[1])));
                float gg = tanhf(acc[2] + bsum[2]);
                float og = 1.f / (1.f + expf(-(acc[3] + bsum[3])));
                creg = fg * creg + ig * gg;
                ASTORE(&hh[(size_t)(t + 1) * HID + rL], og * tanhf(creg));
            }
        }

        // ======== barrier A: single-hop packed flags (h_{t+1} ready) ========
        {
            const unsigned bka = (unsigned)(t + 1);
            __syncthreads();
            if (tid == 0) ASTORE(&flags4[b], bka);
            if (tid < NBLK) {
                int guard = 0;
                while (ALOADF(&flags4[tid]) < bka) {
                    __builtin_amdgcn_s_sleep(1);
                    if (++guard > (1 << 24)) break;
                }
            }
            __syncthreads();
        }

        // ======== stage h_{t+1}: Sh (abs-sum) + Hsum (plain sum) ========
        {
            float sa = 0.f, ss = 0.f;
            if (tid < 256) {
                float4 hv = ((const float4*)(hh + (size_t)(t + 1) * HID))[tid];
                hs4[tid] = hv;
                sa = fabsf(hv.x) + fabsf(hv.y) + fabsf(hv.z) + fabsf(hv.w);
                ss = hv.x + hv.y + hv.z + hv.w;
            }
            #pragma unroll
            for (int off = 32; off > 0; off >>= 1) {
                sa += __shfl_xor(sa, off);
                ss += __shfl_xor(ss, off);
            }
            if (lane == 0) { sred[wave] = sa; sred2[wave] = ss; }
        }
        __syncthreads();
        float Hsum = 0.f;
        Sh = 0.f;
        #pragma unroll
        for (int w = 0; w < 8; ++w) { Sh += sred[w]; Hsum += sred2[w]; }

        const float4 H0 = hs4[lane * 4 + 0];
        const float4 H1 = hs4[lane * 4 + 1];
        const float4 H2 = hs4[lane * 4 + 2];
        const float4 H3 = hs4[lane * 4 + 3];
        const unsigned genN = (unsigned)(t + 1) & 0xFFFFu;

        // ======== screen 25 rows; gen-tagged publishes ========
        ull pmw = 0ull;
        if (jb < NC) {
            float sv = -3.0e38f;      // lane r holds screened value of row r
            #pragma unroll
            for (int rr = 0; rr < GRREG; ++rr) {
                const int j = jb + rr;
                if (j < NC) {
                    float a = dot16u(qb[rr], H0, H1, H2, H3);
                    #pragma unroll
                    for (int off = 32; off > 0; off >>= 1) a += __shfl_xor(a, off);
                    const float v = (a - 128.f * Hsum) * INVSQ + b_head[j];
                    if (lane == rr) sv = v;
                    pmw = umaxu(pmw, packkv(v, (unsigned)j));
                }
            }
            #pragma unroll
            for (int rr = 0; rr < GRLDS; ++rr) {
                const int j = jb + GRREG + rr;
                if (j < NC) {
                    float a = dot16u(w8L[wave][rr][lane], H0, H1, H2, H3);
                    #pragma unroll
                    for (int off = 32; off > 0; off >>= 1) a += __shfl_xor(a, off);
                    const float v = (a - 128.f * Hsum) * INVSQ + b_head[j];
                    if (lane == GRREG + rr) sv = v;
                    pmw = umaxu(pmw, packkv(v, (unsigned)j));
                }
            }
            const float gtop = unford((unsigned)(pmw >> 32));
            const float E2 = QERR * Sh * 1.02f + 1e-4f;
            // store abuf16 only for potential candidates (within 2E of group top)
            if (lane < GR && (jb + lane) < NC && sv >= gtop - 2.0f * E2)
                ASTORE(&abuf16[jb + lane], (ceil16(sv) << 16) | genN);
            if (lane == 0)
                ASTORE(&bm4[g], (ceil16(gtop) << 16) | genN);
        }
        if (lane == 0) wtop[wave] = pmw;

        // ======== barrier B fused with record exchange (mtil for next resolve) ========
        __syncthreads();     // drains abuf16/bm4 stores; wtop visible
        {
            ull bt = wtop[0];
            #pragma unroll
            for (int w = 1; w < 8; ++w) bt = umaxu(bt, wtop[w]);
            if (tid == 0) {
                ull ra;
                if (bt) {
                    unsigned idx32 = 0xFFFFFFFFu - (unsigned)(bt & 0xFFFFFFFFull);
                    unsigned inv16 = 0xFFFFu - (idx32 & 0xFFFFu);
                    ra = ((bt >> 32) << 32) | ((ull)inv16 << 16) | (ull)genN;
                } else {
                    ra = (ull)genN;
                }
                ASTORE(&recA[b], ra);
            }
            ull mt = 0ull;
            if (tid < NBLK) {
                ull rA;
                int guard = 0;
                for (;;) {
                    rA = ALOADF(&recA[tid]);
                    if ((rA & 0xFFFFull) == (ull)genN) break;
                    __builtin_amdgcn_s_sleep(1);
                    if (++guard > (1 << 24)) break;
                }
                mt = rA & ~0xFFFFull;
            }
            #pragma unroll
            for (int off = 32; off > 0; off >>= 1)
                mt = umaxu(mt, shflx_ull(mt, off));
            if (lane == 0) gt8[wave] = mt;
            __syncthreads();
            mt = gt8[0];
            #pragma unroll
            for (int w = 1; w < 8; ++w) mt = umaxu(mt, gt8[w]);
            g_top = mt;
        }
    }

    // ---- final char (block 0 only): rerun resolve for t = TLEN ----
    if (b == 0) {
        const unsigned gen = (unsigned)TLEN & 0xFFFFu;
        const float mtil = unford((unsigned)(g_top >> 32));
        const float E = QERR * Sh * 1.02f + 1e-4f;
        const float thresh = mtil - 2.0f * E;
        const unsigned th16 = ford(thresh) >> 16;
        if (tid == 0) { s_cnt = 0; s_gcnt = 0; }
        __syncthreads();
        {
            uint4 bv = ((const uint4*)bm4)[tid];
            #pragma unroll
            for (int k = 0; k < 4; ++k) {
                unsigned v = (&bv.x)[k];
                if ((v & 0xFFFFu) == gen && (v >> 16) >= th16) {
                    int p = atomicAdd(&s_gcnt, 1);
                    if (p < 32) s_grps[p] = tid * 4 + k;
                }
            }
        }
        __syncthreads();
        const int ngr = s_gcnt < 32 ? s_gcnt : 32;
        for (int gq = wave; gq < ngr; gq += 8) {
            if (lane < GR) {
                const int j = s_grps[gq] * GR + lane;
                if (j < NC) {
                    unsigned a = ALOADF(&abuf16[j]);
                    if ((a & 0xFFFFu) == gen && (a >> 16) >= th16) {
                        int p = atomicAdd(&s_cnt, 1);
                        if (p < CANDR) s_rows[p] = j;
                    }
                }
            }
        }
        __syncthreads();
        const int ncr = s_cnt < CANDR ? s_cnt : CANDR;
        ull best = 0ull;
        for (int q = wave; q < ncr; q += 8) {
            const int j = s_rows[q];
            best = umaxu(best, packkv(exact_logit(hs4, W_head, b_head, j, lane),
                                      (unsigned)j));
        }
        __syncthreads();
        if (lane == 0) red8[wave] = best;
        __syncthreads();
        best = red8[0];
        #pragma unroll
        for (int w = 1; w < 8; ++w) best = umaxu(best, red8[w]);
        unsigned idx = 0xFFFFFFFFu - (unsigned)(best & 0xFFFFFFFFull);
        if (idx >= NC) idx = NC - 1;
        if (tid == 0) chars_out[TLEN - 1] = (float)idx;
    }
}

// ================= phase B: logits[t][j] = W_head[j]·h_t + b_head[j] =================
#define GJ 64
#define GT 128
#define GK 16
__global__ __launch_bounds__(256) void k_gemm(const float* __restrict__ W_head,
                                              const float* __restrict__ b_head,
                                              const float* __restrict__ hh,
                                              float* __restrict__ logits)
{
    __shared__ float Ws[GK][GJ + 4];
    __shared__ float Hs[GK][GT + 1];

    const int tid = threadIdx.x;
    const int j0 = blockIdx.x * GJ;
    const int t0 = blockIdx.y * GT;
    const int tj = tid & 15;
    const int tt = tid >> 4;

    const int wlj = tid >> 2;
    const int wlk = (tid & 3) * 4;
    const int hlt = tid >> 1;
    const int hlk = (tid & 1) * 8;
    const float* Wrow = W_head + (size_t)(j0 + wlj) * HID;
    const bool wvalid = (j0 + wlj) < NC;

    float acc[8][4];
    #pragma unroll
    for (int bb = 0; bb < 8; ++bb)
        #pragma unroll
        for (int a = 0; a < 4; ++a) acc[bb][a] = 0.f;

    for (int k0 = 0; k0 < HID; k0 += GK) {
        __syncthreads();
        float4 wv = wvalid ? *(const float4*)(Wrow + k0 + wlk) : make_float4(0, 0, 0, 0);
        Ws[wlk + 0][wlj] = wv.x; Ws[wlk + 1][wlj] = wv.y;
        Ws[wlk + 2][wlj] = wv.z; Ws[wlk + 3][wlj] = wv.w;
        const float* hp = hh + (size_t)(t0 + hlt + 1) * HID + k0 + hlk;
        float4 a0 = *(const float4*)hp;
        float4 a1 = *(const float4*)(hp + 4);
        Hs[hlk + 0][hlt] = a0.x; Hs[hlk + 1][hlt] = a0.y;
        Hs[hlk + 2][hlt] = a0.z; Hs[hlk + 3][hlt] = a0.w;
        Hs[hlk + 4][hlt] = a1.x; Hs[hlk + 5][hlt] = a1.y;
        Hs[hlk + 6][hlt] = a1.z; Hs[hlk + 7][hlt] = a1.w;
        __syncthreads();
        #pragma unroll
        for (int kk = 0; kk < GK; ++kk) {
            float4 w4 = *(const float4*)&Ws[kk][tj * 4];
            float hvv[8];
            #pragma unroll
            for (int bb = 0; bb < 8; ++bb) hvv[bb] = Hs[kk][tt + 16 * bb];
            #pragma unroll
            for (int bb = 0; bb < 8; ++bb) {
                acc[bb][0] = fmaf(w4.x, hvv[bb], acc[bb][0]);
                acc[bb][1] = fmaf(w4.y, hvv[bb], acc[bb][1]);
                acc[bb][2] = fmaf(w4.z, hvv[bb], acc[bb][2]);
                acc[bb][3] = fmaf(w4.w, hvv[bb], acc[bb][3]);
            }
        }
    }

    const int j = j0 + tj * 4;
    float b0 = (j + 0 < NC) ? b_head[j + 0] : 0.f;
    float b1 = (j + 1 < NC) ? b_head[j + 1] : 0.f;
    float b2 = (j + 2 < NC) ? b_head[j + 2] : 0.f;
    float b3 = (j + 3 < NC) ? b_head[j + 3] : 0.f;
    #pragma unroll
    for (int bb = 0; bb < 8; ++bb) {
        const int t = t0 + tt + 16 * bb;
        float* dst = logits + (size_t)t * NC + j;
        if (j + 3 < NC) {
            f32x4 o = { acc[bb][0] + b0, acc[bb][1] + b1,
                        acc[bb][2] + b2, acc[bb][3] + b3 };
            __builtin_nontemporal_store(o, (f32x4*)dst);
        } else {
            if (j + 0 < NC) dst[0] = acc[bb][0] + b0;
            if (j + 1 < NC) dst[1] = acc[bb][1] + b1;
            if (j + 2 < NC) dst[2] = acc[bb][2] + b2;
        }
    }
}

// ======================================================================
// ===================== fallback (round-1, proven) =====================
// ======================================================================
__global__ __launch_bounds__(256) void k_init_fb(const float* __restrict__ inputs,
                                                 const int* __restrict__ startp,
                                                 float* __restrict__ h0,
                                                 float* __restrict__ c,
                                                 ull* __restrict__ blockmax)
{
    int tid = blockIdx.x * 256 + threadIdx.x;
    if (tid < NBH) blockmax[tid] = (tid == 0) ? packkv(3.0e38f, (unsigned)startp[0]) : 0ull;
    if (tid < HID) { h0[tid] = inputs[tid]; c[tid] = 0.f; }
}

__global__ __launch_bounds__(256) void k_lstm_fb(const float* __restrict__ W_ih,
                                                 const float* __restrict__ W_hh,
                                                 const float* __restrict__ b_ih,
                                                 const float* __restrict__ b_hh,
                                                 const float* __restrict__ embed,
                                                 const ull* __restrict__ blockmax,
                                                 const float* __restrict__ h_in,
                                                 float* __restrict__ h_out,
                                                 float* __restrict__ c,
                                                 float* __restrict__ chars_out,
                                                 int t)
{
    __shared__ float4 xs4[CHARD / 4];
    __shared__ float4 hs4[HID / 4];
    __shared__ ull    red[256];
    const int tid = threadIdx.x;
    ull pm = 0ull;
    for (int i = tid; i < NBH; i += 256) pm = umaxu(pm, blockmax[i]);
    red[tid] = pm;
    __syncthreads();
    for (int s = 128; s > 0; s >>= 1) {
        if (tid < s) red[tid] = umaxu(red[tid], red[tid + s]);
        __syncthreads();
    }
    const unsigned idx = 0xFFFFFFFFu - (unsigned)(red[0] & 0xFFFFFFFFull);
    if (t > 0 && blockIdx.x == 0 && tid == 0) chars_out[t - 1] = (float)idx;
    const float4* ex = (const float4*)(embed + (size_t)idx * CHARD);
    if (tid < 128) xs4[tid] = ex[tid];
    hs4[tid] = ((const float4*)h_in)[tid];
    __syncthreads();
    const int wave = tid >> 6, lane = tid & 63;
    const int r = blockIdx.x * 4 + wave;
    float acc[4];
    #pragma unroll
    for (int q = 0; q < 4; ++q) {
        const float4* wi = (const float4*)(W_ih + (size_t)(q * HID + r) * CHARD);
        const float4* wh = (const float4*)(W_hh + (size_t)(q * HID + r) * HID);
        float a = 0.f;
        #pragma unroll
        for (int m = 0; m < 2; ++m) {
            float4 w = wi[m * 64 + lane], v = xs4[m * 64 + lane];
            a = fmaf(w.x, v.x, a); a = fmaf(w.y, v.y, a);
            a = fmaf(w.z, v.z, a); a = fmaf(w.w, v.w, a);
        }
        #pragma unroll
        for (int m = 0; m < 4; ++m) {
            float4 w = wh[m * 64 + lane], v = hs4[m * 64 + lane];
            a = fmaf(w.x, v.x, a); a = fmaf(w.y, v.y, a);
            a = fmaf(w.z, v.z, a); a = fmaf(w.w, v.w, a);
        }
        acc[q] = a;
    }
    #pragma unroll
    for (int q = 0; q < 4; ++q)
        #pragma unroll
        for (int off = 32; off > 0; off >>= 1) acc[q] += __shfl_xor(acc[q], off);
    if (lane == 0) {
        float zi = acc[0] + b_ih[r]           + b_hh[r];
        float zf = acc[1] + b_ih[HID + r]     + b_hh[HID + r];
        float zg = acc[2] + b_ih[2 * HID + r] + b_hh[2 * HID + r];
        float zo = acc[3] + b_ih[3 * HID + r] + b_hh[3 * HID + r];
        float ig = 1.f / (1.f + expf(-zi));
        float fg = 1.f / (1.f + expf(-zf));
        float gg = tanhf(zg);
        float og = 1.f / (1.f + expf(-zo));
        float cn = fg * c[r] + ig * gg;
        c[r] = cn;
        h_out[r] = og * tanhf(cn);
    }
}

__global__ __launch_bounds__(256) void k_head_fb(const float* __restrict__ W_head,
                                                 const float* __restrict__ b_head,
                                                 const float* __restrict__ h_in,
                                                 float* __restrict__ logits,
                                                 ull* __restrict__ blockmax)
{
    __shared__ float4 hs4[HID / 4];
    __shared__ ull    wmax[4];
    const int tid = threadIdx.x;
    hs4[tid] = ((const float4*)h_in)[tid];
    __syncthreads();
    const int wave = tid >> 6, lane = tid & 63;
    const int base = blockIdx.x * 32 + wave * 8;
    ull pm = 0ull;
    #pragma unroll
    for (int rep = 0; rep < 8; ++rep) {
        const int j = base + rep;
        if (j < NC) {
            const float4* w = (const float4*)(W_head + (size_t)j * HID);
            float a = 0.f;
            #pragma unroll
            for (int m = 0; m < 4; ++m) {
                float4 ww = w[m * 64 + lane], v = hs4[m * 64 + lane];
                a = fmaf(ww.x, v.x, a); a = fmaf(ww.y, v.y, a);
                a = fmaf(ww.z, v.z, a); a = fmaf(ww.w, v.w, a);
            }
            #pragma unroll
            for (int off = 32; off > 0; off >>= 1) a += __shfl_xor(a, off);
            const float v = a + b_head[j];
            if (lane == 0) __builtin_nontemporal_store(v, &logits[j]);
            pm = umaxu(pm, packkv(v, (unsigned)j));
        }
    }
    if (lane == 0) wmax[wave] = pm;
    __syncthreads();
    if (tid == 0)
        blockmax[blockIdx.x] = umaxu(umaxu(wmax[0], wmax[1]), umaxu(wmax[2], wmax[3]));
}

__global__ __launch_bounds__(256) void k_final_fb(const ull* __restrict__ blockmax,
                                                  float* __restrict__ chars_out)
{
    __shared__ ull red[256];
    const int tid = threadIdx.x;
    ull pm = 0ull;
    for (int i = tid; i < NBH; i += 256) pm = umaxu(pm, blockmax[i]);
    red[tid] = pm;
    __syncthreads();
    for (int s = 128; s > 0; s >>= 1) {
        if (tid < s) red[tid] = umaxu(red[tid], red[tid + s]);
        __syncthreads();
    }
    if (tid == 0)
        chars_out[TLEN - 1] = (float)(0xFFFFFFFFu - (unsigned)(red[0] & 0xFFFFFFFFull));
}

// ======================================================================
extern "C" void kernel_launch(void* const* d_in, const int* in_sizes, int n_in,
                              void* d_out, int out_size, void* d_ws, size_t ws_size,
                              hipStream_t stream)
{
    const float* inputs = (const float*)d_in[0];
    const float* embed  = (const float*)d_in[1];
    const float* W_ih   = (const float*)d_in[2];
    const float* W_hh   = (const float*)d_in[3];
    const float* b_ih   = (const float*)d_in[4];
    const float* b_hh   = (const float*)d_in[5];
    const float* W_head = (const float*)d_in[6];
    const float* b_head = (const float*)d_in[7];
    const int*   startp = (const int*)d_in[9];

    float* out        = (float*)d_out;
    float* chars_out  = out;          // [2048]
    float* logits_out = out + TLEN;   // [2048 * 50257]

    char* ws = (char*)d_ws;
    const size_t off_hh  = 0;
    const size_t off_c   = off_hh + (size_t)(TLEN + 1) * HID * 4;
    const size_t off_ab  = (off_c + (size_t)HID * 4 + 15) & ~(size_t)15;   // abuf16: NC u32
    const size_t off_bm  = (off_ab + (size_t)NC * 4 + 15) & ~(size_t)15;   // bm4: NGRP2 u32
    const size_t off_fl  = (off_bm + (size_t)NGRP2 * 4 + 63) & ~(size_t)63;
    const size_t off_ra  = (off_fl + (size_t)(NBLK + 16) * 4 + 63) & ~(size_t)63;
    const size_t off_w8  = (off_ra + (size_t)NBLK * 8 + 15) & ~(size_t)15;
    const size_t need    = off_w8 + (size_t)NC * HID;

    if (ws_size >= need) {
        float*    hh     = (float*)(ws + off_hh);
        float*    c      = (float*)(ws + off_c);
        unsigned* abuf16 = (unsigned*)(ws + off_ab);
        unsigned* bm4    = (unsigned*)(ws + off_bm);
        unsigned* flags4 = (unsigned*)(ws + off_fl);
        ull*      recA   = (ull*)(ws + off_ra);
        u8*       W8     = (u8*)(ws + off_w8);

        hipLaunchKernelGGL(k_init, dim3(8), dim3(256), 0, stream,
                           inputs, hh, c, flags4, recA, bm4, abuf16);
        hipLaunchKernelGGL(k_quant, dim3((NC * HID / 16 + 255) / 256), dim3(256), 0,
                           stream, W_head, W8);
        hipLaunchKernelGGL(k_persist, dim3(NBLK), dim3(NTHR), 0, stream,
                           W_ih, W_hh, b_ih, b_hh, embed, W_head, b_head, W8,
                           hh, abuf16, bm4, chars_out, startp, flags4, recA);
        hipLaunchKernelGGL(k_gemm, dim3((NC + GJ - 1) / GJ, TLEN / GT), dim3(256), 0,
                           stream, W_head, b_head, hh, logits_out);
    } else {
        // fallback: round-1 path (needs ~25 KB ws)
        float* h0 = (float*)(ws);
        float* h1 = (float*)(ws + 4096);
        float* c  = (float*)(ws + 8192);
        ull* blockmax = (ull*)(ws + 12288);
        hipLaunchKernelGGL(k_init_fb, dim3(7), dim3(256), 0, stream,
                           inputs, startp, h0, c, blockmax);
        for (int t = 0; t < TLEN; ++t) {
            const float* hin = (t & 1) ? h1 : h0;
            float*       hout = (t & 1) ? h0 : h1;
            hipLaunchKernelGGL(k_lstm_fb, dim3(256), dim3(256), 0, stream,
                               W_ih, W_hh, b_ih, b_hh, embed, blockmax,
                               hin, hout, c, chars_out, t);
            hipLaunchKernelGGL(k_head_fb, dim3(NBH), dim3(256), 0, stream,
                               W_head, b_head, hout,
                               logits_out + (size_t)t * NC, blockmax);
        }
        hipLaunchKernelGGL(k_final_fb, dim3(1), dim3(256), 0, stream, blockmax, chars_out);
    }
}

// Round 14
// 45416.168 us; speedup vs baseline: 1.9804x; 1.1580x over previous
//
#include <hip/hip_runtime.h>
#include <stdint.h>
#include <math.h>

#define HID   1024
#define CHARD 512
#define NC    50257
#define TLEN  2048
#define NBLK  256           // persistent blocks (one per CU)
#define NTHR  512           // threads per persistent block (8 waves)
#define NGRP2 2048          // screen groups (one 25-row group per wave-slot)
#define GR    25
#define GRREG 6             // screen rows held in VGPRs per wave
#define GRLDS 19            // screen rows held in LDS per wave
#define NBH   1571          // fallback head blocks
#define SQ    4064.0f       // 127 / 0.03125
#define INVSQ (1.0f/4064.0f)
#define QERR  (0.5f/4064.0f)
#define CANDR 192
#define FLAGSTRIDE 16       // 64B per flag line

typedef unsigned long long ull;
typedef unsigned char u8;
typedef float f32x4 __attribute__((ext_vector_type(4)));

__device__ __forceinline__ unsigned ford(float f) {
    unsigned b = __float_as_uint(f);
    return (b & 0x80000000u) ? ~b : (b | 0x80000000u);
}
__device__ __forceinline__ float unford(unsigned u) {
    return __uint_as_float((u & 0x80000000u) ? (u & 0x7FFFFFFFu) : ~u);
}
__device__ __forceinline__ ull packkv(float v, unsigned j) {
    return ((ull)ford(v) << 32) | (ull)(0xFFFFFFFFu - j);
}
__device__ __forceinline__ unsigned ceil16(float v) {   // 16-bit ford, rounded UP
    unsigned u = ford(v);
    return (u >> 16) + ((u & 0xFFFFu) ? 1u : 0u);
}
__device__ __forceinline__ ull umaxu(ull a, ull b) { return a > b ? a : b; }
__device__ __forceinline__ ull shflx_ull(ull v, int m) {
    unsigned lo = (unsigned)v, hi = (unsigned)(v >> 32);
    lo = __shfl_xor(lo, m);
    hi = __shfl_xor(hi, m);
    return ((ull)hi << 32) | lo;
}

#define ALOADF(p)    __hip_atomic_load((p), __ATOMIC_RELAXED, __HIP_MEMORY_SCOPE_AGENT)
#define ASTORE(p, v) __hip_atomic_store((p), (v), __ATOMIC_RELAXED, __HIP_MEMORY_SCOPE_AGENT)

// ====== init: hh[0]=inputs, c=0, zero flags+gen lines, bm4, abuf16 ======
__global__ __launch_bounds__(256) void k_init(const float* __restrict__ inputs,
                                              float* __restrict__ hh,
                                              float* __restrict__ c,
                                              unsigned* __restrict__ flagarea,
                                              unsigned* __restrict__ bm4,
                                              unsigned* __restrict__ abuf16)
{
    int g = blockIdx.x * 256 + threadIdx.x;
    if (g < HID) { hh[g] = inputs[g]; c[g] = 0.f; }
    for (int i = g; i < 2 * NBLK * FLAGSTRIDE; i += 2048) flagarea[i] = 0u;
    if (g < NGRP2) bm4[g] = 0u;
    for (int i = g; i < NC; i += 2048) abuf16[i] = 0u;
}

// ================= quantize W_head -> biased uint8: round(w*SQ)+128 =================
__global__ __launch_bounds__(256) void k_quant(const float* __restrict__ W,
                                               u8* __restrict__ W8)
{
    size_t base = ((size_t)blockIdx.x * 256 + threadIdx.x) * 16;
    if (base >= (size_t)NC * HID) return;
    const float4* src = (const float4*)(W + base);
    uint out[4];
    #pragma unroll
    for (int g = 0; g < 4; ++g) {
        float4 w = src[g];
        int a0 = (__float2int_rn(w.x * SQ) + 128) & 255;
        int a1 = (__float2int_rn(w.y * SQ) + 128) & 255;
        int a2 = (__float2int_rn(w.z * SQ) + 128) & 255;
        int a3 = (__float2int_rn(w.w * SQ) + 128) & 255;
        out[g] = (uint)(a0 | (a1 << 8) | (a2 << 16) | (a3 << 24));
    }
    *(uint4*)(W8 + base) = make_uint4(out[0], out[1], out[2], out[3]);
}

// ================= exact fp32 dot of W_head row j with staged h =================
__device__ __forceinline__ float exact_logit(const float4* hs4,
                                             const float* __restrict__ W_head,
                                             const float* __restrict__ b_head,
                                             int j, int lane)
{
    const float4* wr = (const float4*)(W_head + (size_t)j * HID);
    float a = 0.f;
    #pragma unroll
    for (int m = 0; m < 4; ++m) {
        float4 w = wr[m * 64 + lane], v = hs4[m * 64 + lane];
        a = fmaf(w.x, v.x, a); a = fmaf(w.y, v.y, a);
        a = fmaf(w.z, v.z, a); a = fmaf(w.w, v.w, a);
    }
    #pragma unroll
    for (int off = 32; off > 0; off >>= 1) a += __shfl_xor(a, off);
    return a + b_head[j];
}

// ====== slim exact resolve: one bm4 scan yields mtil AND candidate groups ======
__device__ unsigned resolve_slim(const float4* hs4,
                                 const unsigned* bm4, const unsigned* abuf16,
                                 const float* __restrict__ W_head,
                                 const float* __restrict__ b_head,
                                 float Sh, unsigned gen16, int tid)
{
    __shared__ int s_cnt, s_gcnt;
    __shared__ int s_grps[32];
    __shared__ int s_rows[CANDR];
    __shared__ unsigned mred[8];
    __shared__ ull red8[8];

    const int wave = tid >> 6;
    const int lane = tid & 63;

    // pass 1+2a fused: load 4 gen-tagged group maxima per thread (coherent loads)
    unsigned bv[4];
    unsigned m16 = 0u;
    #pragma unroll
    for (int k = 0; k < 4; ++k) {
        bv[k] = ALOADF(&bm4[tid * 4 + k]);
        if ((bv[k] & 0xFFFFu) == gen16) {
            unsigned v = bv[k] >> 16;
            if (v > m16) m16 = v;
        }
    }
    if (tid == 0) { s_cnt = 0; s_gcnt = 0; }
    #pragma unroll
    for (int off = 32; off > 0; off >>= 1) {
        unsigned o = __shfl_xor(m16, off);
        if (o > m16) m16 = o;
    }
    if (lane == 0) mred[wave] = m16;
    __syncthreads();
    m16 = mred[0];
    #pragma unroll
    for (int w = 1; w < 8; ++w) if (mred[w] > m16) m16 = mred[w];

    // conservative threshold: use prev-representable of ceil'd max, minus 2E
    const float mtil_f = unford((m16 > 0 ? m16 - 1 : 0) << 16);
    const float E = QERR * Sh * 1.02f + 1e-4f;
    const float thresh = mtil_f - 2.0f * E;
    const unsigned th16 = ford(thresh) >> 16;

    // candidate-group collection from already-loaded registers
    #pragma unroll
    for (int k = 0; k < 4; ++k) {
        unsigned v = bv[k];
        if ((v & 0xFFFFu) == gen16 && (v >> 16) >= th16) {
            int p = atomicAdd(&s_gcnt, 1);
            if (p < 32) s_grps[p] = tid * 4 + k;
        }
    }
    __syncthreads();
    const int ngr = s_gcnt;
    int ncr;
    if (ngr <= 32) {
        for (int gq = wave; gq < ngr; gq += 8) {
            if (lane < GR) {
                const int j = s_grps[gq] * GR + lane;
                if (j < NC) {
                    unsigned a = ALOADF(&abuf16[j]);
                    if ((a & 0xFFFFu) == gen16 && (a >> 16) >= th16) {
                        int p = atomicAdd(&s_cnt, 1);
                        if (p < CANDR) s_rows[p] = j;
                    }
                }
            }
        }
        __syncthreads();
        ncr = s_cnt;
    } else ncr = CANDR + 1;

    ull best = 0ull;
    if (ncr <= CANDR) {
        for (int q = wave; q < ncr; q += 8) {
            const int j = s_rows[q];
            best = umaxu(best, packkv(exact_logit(hs4, W_head, b_head, j, lane),
                                      (unsigned)j));
        }
    } else {
        // pathological overflow: exhaustive gen-checked scan
        for (int i = wave; i < NGRP2; i += 8) {
            unsigned v = ALOADF(&bm4[i]);
            if ((v & 0xFFFFu) == gen16 && (v >> 16) >= th16) {
                const int j0 = i * GR;
                bool c = false;
                if (lane < GR && j0 + lane < NC) {
                    unsigned a = ALOADF(&abuf16[j0 + lane]);
                    c = ((a & 0xFFFFu) == gen16 && (a >> 16) >= th16);
                }
                ull cnd = __ballot(c);
                while (cnd) {
                    const int s = __builtin_ctzll(cnd);
                    cnd &= cnd - 1;
                    const int j = j0 + s;
                    best = umaxu(best, packkv(exact_logit(hs4, W_head, b_head, j, lane),
                                              (unsigned)j));
                }
            }
        }
    }
    __syncthreads();
    if (lane == 0) red8[wave] = best;
    __syncthreads();
    best = red8[0];
    #pragma unroll
    for (int w = 1; w < 8; ++w) best = umaxu(best, red8[w]);
    unsigned idx = 0xFFFFFFFFu - (unsigned)(best & 0xFFFFFFFFull);
    return idx < NC ? idx : (NC - 1);
}

// ================= biased-uint8 16-element dot =================
__device__ __forceinline__ float dot16u(uint4 q, float4 h0, float4 h1,
                                        float4 h2, float4 h3)
{
    float a = 0.f;
    a = fmaf((float)(q.x & 255u), h0.x, a);
    a = fmaf((float)((q.x >> 8) & 255u), h0.y, a);
    a = fmaf((float)((q.x >> 16) & 255u), h0.z, a);
    a = fmaf((float)(q.x >> 24), h0.w, a);
    a = fmaf((float)(q.y & 255u), h1.x, a);
    a = fmaf((float)((q.y >> 8) & 255u), h1.y, a);
    a = fmaf((float)((q.y >> 16) & 255u), h1.z, a);
    a = fmaf((float)(q.y >> 24), h1.w, a);
    a = fmaf((float)(q.z & 255u), h2.x, a);
    a = fmaf((float)((q.z >> 8) & 255u), h2.y, a);
    a = fmaf((float)((q.z >> 16) & 255u), h2.z, a);
    a = fmaf((float)(q.z >> 24), h2.w, a);
    a = fmaf((float)(q.w & 255u), h3.x, a);
    a = fmaf((float)((q.w >> 8) & 255u), h3.y, a);
    a = fmaf((float)((q.w >> 16) & 255u), h3.z, a);
    a = fmaf((float)(q.w >> 24), h3.w, a);
    return a;
}

// ===== persistent kernel: r10 private-line barrier + slim gen-tagged resolve =====
__global__ __launch_bounds__(NTHR, 1) void k_persist(
    const float* __restrict__ W_ih, const float* __restrict__ W_hh,
    const float* __restrict__ b_ih, const float* __restrict__ b_hh,
    const float* __restrict__ embed,
    const float* __restrict__ W_head, const float* __restrict__ b_head,
    const u8* __restrict__ W8,
    float* hh, unsigned* abuf16, unsigned* bm4,
    float* __restrict__ chars_out, const int* __restrict__ startp,
    unsigned* flags, unsigned* gen)
{
    __shared__ uint4  w8L[8][GRLDS][64];     // 152 KB
    __shared__ float4 hs4[HID / 4];          // 4 KB
    __shared__ float4 xs4[CHARD / 4];        // 2 KB
    __shared__ float  sred[8], sred2[8];

    const int b    = blockIdx.x;
    const int tid  = threadIdx.x;
    const int wave = tid >> 6;
    const int lane = tid & 63;
    const int rL   = b * 4 + wave;       // LSTM row for waves 0-3
    const int g    = b * 8 + wave;       // screen group
    const int jb   = g * GR;
    const u8* Wp   = W8 + (size_t)jb * HID;

    // ---- persistent W8 slice: rows 0..5 -> VGPRs, rows 6..24 -> LDS ----
    uint4 qb[GRREG];
    #pragma unroll
    for (int rr = 0; rr < GRREG; ++rr) {
        const int j = jb + rr;
        qb[rr] = (j < NC) ? ((const uint4*)(Wp + (size_t)rr * HID))[lane]
                          : make_uint4(0, 0, 0, 0);
    }
    #pragma unroll
    for (int rr = 0; rr < GRLDS; ++rr) {
        const int j = jb + GRREG + rr;
        w8L[wave][rr][lane] = (j < NC)
            ? ((const uint4*)(Wp + (size_t)(GRREG + rr) * HID))[lane]
            : make_uint4(0, 0, 0, 0);
    }

    float bsum[4] = {0.f, 0.f, 0.f, 0.f};
    if (wave < 4) {
        #pragma unroll
        for (int q = 0; q < 4; ++q) bsum[q] = b_ih[q * HID + rL] + b_hh[q * HID + rL];
    }
    float creg = 0.f;
    __syncthreads();

    // ---- stage h0 + Sh ----
    float Sh;
    {
        float sa = 0.f;
        if (tid < 256) {
            float4 hv = ((const float4*)hh)[tid];
            hs4[tid] = hv;
            sa = fabsf(hv.x) + fabsf(hv.y) + fabsf(hv.z) + fabsf(hv.w);
        }
        #pragma unroll
        for (int off = 32; off > 0; off >>= 1) sa += __shfl_xor(sa, off);
        if (lane == 0) sred[wave] = sa;
        __syncthreads();
        Sh = 0.f;
        #pragma unroll
        for (int w = 0; w < 8; ++w) Sh += sred[w];
    }

    unsigned bk = 0;

    // r10-proven contention-free barrier:
    //  arrival: block b stores flags[b*FS]; block0 threads each poll ONE line.
    //  release: block0 threads store gen[tid*FS] (private line per block);
    //           block b's tid0 polls ONLY gen[b*FS] -> 1 reader + 1 writer per line.
    #define GRIDBAR()                                                              \
    do {                                                                           \
        ++bk;                                                                      \
        __syncthreads();                                                           \
        if (b == 0) {                                                              \
            if (tid > 0 && tid < NBLK) {                                           \
                int guard = 0;                                                     \
                while (ALOADF(&flags[tid * FLAGSTRIDE]) < bk) {                    \
                    __builtin_amdgcn_s_sleep(1);                                   \
                    if (++guard > (1 << 24)) break;                                \
                }                                                                  \
            }                                                                      \
            __syncthreads();                                                       \
            if (tid < NBLK)                                                        \
                ASTORE(&gen[tid * FLAGSTRIDE], bk);                                \
        } else {                                                                   \
            if (tid == 0) {                                                        \
                ASTORE(&flags[b * FLAGSTRIDE], bk);                                \
                int guard = 0;                                                     \
                while (ALOADF(&gen[b * FLAGSTRIDE]) < bk) {                        \
                    __builtin_amdgcn_s_sleep(1);                                   \
                    if (++guard > (1 << 24)) break;                                \
                }                                                                  \
            }                                                                      \
            __syncthreads();                                                       \
        }                                                                          \
    } while (0)

    for (int t = 0; t < TLEN; ++t) {
        // ---- resolve prev argmax (exact; slim gen-tagged) ----
        unsigned idx;
        if (t == 0) {
            idx = (unsigned)startp[0];
        } else {
            idx = resolve_slim(hs4, bm4, abuf16, W_head, b_head, Sh,
                               (unsigned)t & 0xFFFFu, tid);
            if (b == 0 && tid == 0) chars_out[t - 1] = (float)idx;
        }
        if (tid < 128) xs4[tid] = ((const float4*)(embed + (size_t)idx * CHARD))[tid];
        __syncthreads();

        // ---- LSTM (waves 0-3, weights streamed from L2) ----
        if (wave < 4) {
            float acc[4];
            #pragma unroll
            for (int q = 0; q < 4; ++q) {
                const float4* wi = (const float4*)(W_ih + (size_t)(q * HID + rL) * CHARD);
                const float4* wh = (const float4*)(W_hh + (size_t)(q * HID + rL) * HID);
                float a = 0.f;
                #pragma unroll
                for (int m = 0; m < 2; ++m) {
                    float4 w = wi[m * 64 + lane], v = xs4[m * 64 + lane];
                    a = fmaf(w.x, v.x, a); a = fmaf(w.y, v.y, a);
                    a = fmaf(w.z, v.z, a); a = fmaf(w.w, v.w, a);
                }
                #pragma unroll
                for (int m = 0; m < 4; ++m) {
                    float4 w = wh[m * 64 + lane], v = hs4[m * 64 + lane];
                    a = fmaf(w.x, v.x, a); a = fmaf(w.y, v.y, a);
                    a = fmaf(w.z, v.z, a); a = fmaf(w.w, v.w, a);
                }
                acc[q] = a;
            }
            #pragma unroll
            for (int q = 0; q < 4; ++q) {
                #pragma unroll
                for (int off = 32; off > 0; off >>= 1) acc[q] += __shfl_xor(acc[q], off);
            }
            if (lane == 0) {
                float ig = 1.f / (1.f + expf(-(acc[0] + bsum[0])));
                float fg = 1.f / (1.f + expf(-(acc[1] + bsum[1])));
                float gg = tanhf(acc[2] + bsum[2]);
                float og = 1.f / (1.f + expf(-(acc[3] + bsum[3])));
                creg = fg * creg + ig * gg;
                ASTORE(&hh[(size_t)(t + 1) * HID + rL], og * tanhf(creg));
            }
        }

        GRIDBAR();   // h_{t+1} complete

        // ---- stage h_{t+1}: Sh (abs-sum) + Hsum (plain sum) ----
        {
            float sa = 0.f, ss = 0.f;
            if (tid < 256) {
                float4 hv = ((const float4*)(hh + (size_t)(t + 1) * HID))[tid];
                hs4[tid] = hv;
                sa = fabsf(hv.x) + fabsf(hv.y) + fabsf(hv.z) + fabsf(hv.w);
                ss = hv.x + hv.y + hv.z + hv.w;
            }
            #pragma unroll
            for (int off = 32; off > 0; off >>= 1) {
                sa += __shfl_xor(sa, off);
                ss += __shfl_xor(ss, off);
            }
            if (lane == 0) { sred[wave] = sa; sred2[wave] = ss; }
        }
        __syncthreads();
        float Hsum = 0.f;
        Sh = 0.f;
        #pragma unroll
        for (int w = 0; w < 8; ++w) { Sh += sred[w]; Hsum += sred2[w]; }

        const float4 H0 = hs4[lane * 4 + 0];
        const float4 H1 = hs4[lane * 4 + 1];
        const float4 H2 = hs4[lane * 4 + 2];
        const float4 H3 = hs4[lane * 4 + 3];
        const unsigned genN = (unsigned)(t + 1) & 0xFFFFu;

        // ---- screen 25 rows; gen-tagged candidate-only publishes ----
        if (jb < NC) {
            ull pmw = 0ull;
            float sv = -3.0e38f;      // lane r holds screened value of row r
            #pragma unroll
            for (int rr = 0; rr < GRREG; ++rr) {
                const int j = jb + rr;
                if (j < NC) {
                    float a = dot16u(qb[rr], H0, H1, H2, H3);
                    #pragma unroll
                    for (int off = 32; off > 0; off >>= 1) a += __shfl_xor(a, off);
                    const float v = (a - 128.f * Hsum) * INVSQ + b_head[j];
                    if (lane == rr) sv = v;
                    pmw = umaxu(pmw, packkv(v, (unsigned)j));
                }
            }
            #pragma unroll
            for (int rr = 0; rr < GRLDS; ++rr) {
                const int j = jb + GRREG + rr;
                if (j < NC) {
                    float a = dot16u(w8L[wave][rr][lane], H0, H1, H2, H3);
                    #pragma unroll
                    for (int off = 32; off > 0; off >>= 1) a += __shfl_xor(a, off);
                    const float v = (a - 128.f * Hsum) * INVSQ + b_head[j];
                    if (lane == GRREG + rr) sv = v;
                    pmw = umaxu(pmw, packkv(v, (unsigned)j));
                }
            }
            const float gtop = unford((unsigned)(pmw >> 32));
            const float E2 = QERR * Sh * 1.02f + 1e-4f;
            if (lane < GR && (jb + lane) < NC && sv >= gtop - 2.0f * E2)
                ASTORE(&abuf16[jb + lane], (ceil16(sv) << 16) | genN);
            if (lane == 0)
                ASTORE(&bm4[g], (ceil16(gtop) << 16) | genN);
        }

        GRIDBAR();   // bm4/abuf16 complete
    }

    // ---- final char (block 0 only) ----
    if (b == 0) {
        unsigned idx = resolve_slim(hs4, bm4, abuf16, W_head, b_head, Sh,
                                    (unsigned)TLEN & 0xFFFFu, tid);
        if (tid == 0) chars_out[TLEN - 1] = (float)idx;
    }
    #undef GRIDBAR
}

// ================= phase B: logits[t][j] = W_head[j]·h_t + b_head[j] =================
#define GJ 64
#define GT 128
#define GK 16
__global__ __launch_bounds__(256) void k_gemm(const float* __restrict__ W_head,
                                              const float* __restrict__ b_head,
                                              const float* __restrict__ hh,
                                              float* __restrict__ logits)
{
    __shared__ float Ws[GK][GJ + 4];
    __shared__ float Hs[GK][GT + 1];

    const int tid = threadIdx.x;
    const int j0 = blockIdx.x * GJ;
    const int t0 = blockIdx.y * GT;
    const int tj = tid & 15;
    const int tt = tid >> 4;

    const int wlj = tid >> 2;
    const int wlk = (tid & 3) * 4;
    const int hlt = tid >> 1;
    const int hlk = (tid & 1) * 8;
    const float* Wrow = W_head + (size_t)(j0 + wlj) * HID;
    const bool wvalid = (j0 + wlj) < NC;

    float acc[8][4];
    #pragma unroll
    for (int bb = 0; bb < 8; ++bb)
        #pragma unroll
        for (int a = 0; a < 4; ++a) acc[bb][a] = 0.f;

    for (int k0 = 0; k0 < HID; k0 += GK) {
        __syncthreads();
        float4 wv = wvalid ? *(const float4*)(Wrow + k0 + wlk) : make_float4(0, 0, 0, 0);
        Ws[wlk + 0][wlj] = wv.x; Ws[wlk + 1][wlj] = wv.y;
        Ws[wlk + 2][wlj] = wv.z; Ws[wlk + 3][wlj] = wv.w;
        const float* hp = hh + (size_t)(t0 + hlt + 1) * HID + k0 + hlk;
        float4 a0 = *(const float4*)hp;
        float4 a1 = *(const float4*)(hp + 4);
        Hs[hlk + 0][hlt] = a0.x; Hs[hlk + 1][hlt] = a0.y;
        Hs[hlk + 2][hlt] = a0.z; Hs[hlk + 3][hlt] = a0.w;
        Hs[hlk + 4][hlt] = a1.x; Hs[hlk + 5][hlt] = a1.y;
        Hs[hlk + 6][hlt] = a1.z; Hs[hlk + 7][hlt] = a1.w;
        __syncthreads();
        #pragma unroll
        for (int kk = 0; kk < GK; ++kk) {
            float4 w4 = *(const float4*)&Ws[kk][tj * 4];
            float hvv[8];
            #pragma unroll
            for (int bb = 0; bb < 8; ++bb) hvv[bb] = Hs[kk][tt + 16 * bb];
            #pragma unroll
            for (int bb = 0; bb < 8; ++bb) {
                acc[bb][0] = fmaf(w4.x, hvv[bb], acc[bb][0]);
                acc[bb][1] = fmaf(w4.y, hvv[bb], acc[bb][1]);
                acc[bb][2] = fmaf(w4.z, hvv[bb], acc[bb][2]);
                acc[bb][3] = fmaf(w4.w, hvv[bb], acc[bb][3]);
            }
        }
    }

    const int j = j0 + tj * 4;
    float b0 = (j + 0 < NC) ? b_head[j + 0] : 0.f;
    float b1 = (j + 1 < NC) ? b_head[j + 1] : 0.f;
    float b2 = (j + 2 < NC) ? b_head[j + 2] : 0.f;
    float b3 = (j + 3 < NC) ? b_head[j + 3] : 0.f;
    #pragma unroll
    for (int bb = 0; bb < 8; ++bb) {
        const int t = t0 + tt + 16 * bb;
        float* dst = logits + (size_t)t * NC + j;
        if (j + 3 < NC) {
            f32x4 o = { acc[bb][0] + b0, acc[bb][1] + b1,
                        acc[bb][2] + b2, acc[bb][3] + b3 };
            __builtin_nontemporal_store(o, (f32x4*)dst);
        } else {
            if (j + 0 < NC) dst[0] = acc[bb][0] + b0;
            if (j + 1 < NC) dst[1] = acc[bb][1] + b1;
            if (j + 2 < NC) dst[2] = acc[bb][2] + b2;
        }
    }
}

// ======================================================================
// ===================== fallback (round-1, proven) =====================
// ======================================================================
__global__ __launch_bounds__(256) void k_init_fb(const float* __restrict__ inputs,
                                                 const int* __restrict__ startp,
                                                 float* __restrict__ h0,
                                                 float* __restrict__ c,
                                                 ull* __restrict__ blockmax)
{
    int tid = blockIdx.x * 256 + threadIdx.x;
    if (tid < NBH) blockmax[tid] = (tid == 0) ? packkv(3.0e38f, (unsigned)startp[0]) : 0ull;
    if (tid < HID) { h0[tid] = inputs[tid]; c[tid] = 0.f; }
}

__global__ __launch_bounds__(256) void k_lstm_fb(const float* __restrict__ W_ih,
                                                 const float* __restrict__ W_hh,
                                                 const float* __restrict__ b_ih,
                                                 const float* __restrict__ b_hh,
                                                 const float* __restrict__ embed,
                                                 const ull* __restrict__ blockmax,
                                                 const float* __restrict__ h_in,
                                                 float* __restrict__ h_out,
                                                 float* __restrict__ c,
                                                 float* __restrict__ chars_out,
                                                 int t)
{
    __shared__ float4 xs4[CHARD / 4];
    __shared__ float4 hs4[HID / 4];
    __shared__ ull    red[256];
    const int tid = threadIdx.x;
    ull pm = 0ull;
    for (int i = tid; i < NBH; i += 256) pm = umaxu(pm, blockmax[i]);
    red[tid] = pm;
    __syncthreads();
    for (int s = 128; s > 0; s >>= 1) {
        if (tid < s) red[tid] = umaxu(red[tid], red[tid + s]);
        __syncthreads();
    }
    const unsigned idx = 0xFFFFFFFFu - (unsigned)(red[0] & 0xFFFFFFFFull);
    if (t > 0 && blockIdx.x == 0 && tid == 0) chars_out[t - 1] = (float)idx;
    const float4* ex = (const float4*)(embed + (size_t)idx * CHARD);
    if (tid < 128) xs4[tid] = ex[tid];
    hs4[tid] = ((const float4*)h_in)[tid];
    __syncthreads();
    const int wave = tid >> 6, lane = tid & 63;
    const int r = blockIdx.x * 4 + wave;
    float acc[4];
    #pragma unroll
    for (int q = 0; q < 4; ++q) {
        const float4* wi = (const float4*)(W_ih + (size_t)(q * HID + r) * CHARD);
        const float4* wh = (const float4*)(W_hh + (size_t)(q * HID + r) * HID);
        float a = 0.f;
        #pragma unroll
        for (int m = 0; m < 2; ++m) {
            float4 w = wi[m * 64 + lane], v = xs4[m * 64 + lane];
            a = fmaf(w.x, v.x, a); a = fmaf(w.y, v.y, a);
            a = fmaf(w.z, v.z, a); a = fmaf(w.w, v.w, a);
        }
        #pragma unroll
        for (int m = 0; m < 4; ++m) {
            float4 w = wh[m * 64 + lane], v = hs4[m * 64 + lane];
            a = fmaf(w.x, v.x, a); a = fmaf(w.y, v.y, a);
            a = fmaf(w.z, v.z, a); a = fmaf(w.w, v.w, a);
        }
        acc[q] = a;
    }
    #pragma unroll
    for (int q = 0; q < 4; ++q)
        #pragma unroll
        for (int off = 32; off > 0; off >>= 1) acc[q] += __shfl_xor(acc[q], off);
    if (lane == 0) {
        float zi = acc[0] + b_ih[r]           + b_hh[r];
        float zf = acc[1] + b_ih[HID + r]     + b_hh[HID + r];
        float zg = acc[2] + b_ih[2 * HID + r] + b_hh[2 * HID + r];
        float zo = acc[3] + b_ih[3 * HID + r] + b_hh[3 * HID + r];
        float ig = 1.f / (1.f + expf(-zi));
        float fg = 1.f / (1.f + expf(-zf));
        float gg = tanhf(zg);
        float og = 1.f / (1.f + expf(-zo));
        float cn = fg * c[r] + ig * gg;
        c[r] = cn;
        h_out[r] = og * tanhf(cn);
    }
}

__global__ __launch_bounds__(256) void k_head_fb(const float* __restrict__ W_head,
                                                 const float* __restrict__ b_head,
                                                 const float* __restrict__ h_in,
                                                 float* __restrict__ logits,
                                                 ull* __restrict__ blockmax)
{
    __shared__ float4 hs4[HID / 4];
    __shared__ ull    wmax[4];
    const int tid = threadIdx.x;
    hs4[tid] = ((const float4*)h_in)[tid];
    __syncthreads();
    const int wave = tid >> 6, lane = tid & 63;
    const int base = blockIdx.x * 32 + wave * 8;
    ull pm = 0ull;
    #pragma unroll
    for (int rep = 0; rep < 8; ++rep) {
        const int j = base + rep;
        if (j < NC) {
            const float4* w = (const float4*)(W_head + (size_t)j * HID);
            float a = 0.f;
            #pragma unroll
            for (int m = 0; m < 4; ++m) {
                float4 ww = w[m * 64 + lane], v = hs4[m * 64 + lane];
                a = fmaf(ww.x, v.x, a); a = fmaf(ww.y, v.y, a);
                a = fmaf(ww.z, v.z, a); a = fmaf(ww.w, v.w, a);
            }
            #pragma unroll
            for (int off = 32; off > 0; off >>= 1) a += __shfl_xor(a, off);
            const float v = a + b_head[j];
            if (lane == 0) __builtin_nontemporal_store(v, &logits[j]);
            pm = umaxu(pm, packkv(v, (unsigned)j));
        }
    }
    if (lane == 0) wmax[wave] = pm;
    __syncthreads();
    if (tid == 0)
        blockmax[blockIdx.x] = umaxu(umaxu(wmax[0], wmax[1]), umaxu(wmax[2], wmax[3]));
}

__global__ __launch_bounds__(256) void k_final_fb(const ull* __restrict__ blockmax,
                                                  float* __restrict__ chars_out)
{
    __shared__ ull red[256];
    const int tid = threadIdx.x;
    ull pm = 0ull;
    for (int i = tid; i < NBH; i += 256) pm = umaxu(pm, blockmax[i]);
    red[tid] = pm;
    __syncthreads();
    for (int s = 128; s > 0; s >>= 1) {
        if (tid < s) red[tid] = umaxu(red[tid], red[tid + s]);
        __syncthreads();
    }
    if (tid == 0)
        chars_out[TLEN - 1] = (float)(0xFFFFFFFFu - (unsigned)(red[0] & 0xFFFFFFFFull));
}

// ======================================================================
extern "C" void kernel_launch(void* const* d_in, const int* in_sizes, int n_in,
                              void* d_out, int out_size, void* d_ws, size_t ws_size,
                              hipStream_t stream)
{
    const float* inputs = (const float*)d_in[0];
    const float* embed  = (const float*)d_in[1];
    const float* W_ih   = (const float*)d_in[2];
    const float* W_hh   = (const float*)d_in[3];
    const float* b_ih   = (const float*)d_in[4];
    const float* b_hh   = (const float*)d_in[5];
    const float* W_head = (const float*)d_in[6];
    const float* b_head = (const float*)d_in[7];
    const int*   startp = (const int*)d_in[9];

    float* out        = (float*)d_out;
    float* chars_out  = out;          // [2048]
    float* logits_out = out + TLEN;   // [2048 * 50257]

    char* ws = (char*)d_ws;
    const size_t off_hh  = 0;
    const size_t off_c   = off_hh + (size_t)(TLEN + 1) * HID * 4;
    const size_t off_ab  = (off_c + (size_t)HID * 4 + 15) & ~(size_t)15;   // abuf16: NC u32
    const size_t off_bm  = (off_ab + (size_t)NC * 4 + 15) & ~(size_t)15;   // bm4: NGRP2 u32
    const size_t off_fl  = (off_bm + (size_t)NGRP2 * 4 + 63) & ~(size_t)63;
    const size_t off_w8  = (off_fl + (size_t)(2 * NBLK * FLAGSTRIDE) * 4 + 15)
                           & ~(size_t)15;
    const size_t need    = off_w8 + (size_t)NC * HID;

    if (ws_size >= need) {
        float*    hh     = (float*)(ws + off_hh);
        float*    c      = (float*)(ws + off_c);
        unsigned* abuf16 = (unsigned*)(ws + off_ab);
        unsigned* bm4    = (unsigned*)(ws + off_bm);
        unsigned* flags  = (unsigned*)(ws + off_fl);
        unsigned* gen    = flags + NBLK * FLAGSTRIDE;
        u8*       W8     = (u8*)(ws + off_w8);

        hipLaunchKernelGGL(k_init, dim3(8), dim3(256), 0, stream,
                           inputs, hh, c, flags, bm4, abuf16);
        hipLaunchKernelGGL(k_quant, dim3((NC * HID / 16 + 255) / 256), dim3(256), 0,
                           stream, W_head, W8);
        hipLaunchKernelGGL(k_persist, dim3(NBLK), dim3(NTHR), 0, stream,
                           W_ih, W_hh, b_ih, b_hh, embed, W_head, b_head, W8,
                           hh, abuf16, bm4, chars_out, startp, flags, gen);
        hipLaunchKernelGGL(k_gemm, dim3((NC + GJ - 1) / GJ, TLEN / GT), dim3(256), 0,
                           stream, W_head, b_head, hh, logits_out);
    } else {
        // fallback: round-1 path (needs ~25 KB ws)
        float* h0 = (float*)(ws);
        float* h1 = (float*)(ws + 4096);
        float* c  = (float*)(ws + 8192);
        ull* blockmax = (ull*)(ws + 12288);
        hipLaunchKernelGGL(k_init_fb, dim3(7), dim3(256), 0, stream,
                           inputs, startp, h0, c, blockmax);
        for (int t = 0; t < TLEN; ++t) {
            const float* hin = (t & 1) ? h1 : h0;
            float*       hout = (t & 1) ? h0 : h1;
            hipLaunchKernelGGL(k_lstm_fb, dim3(256), dim3(256), 0, stream,
                               W_ih, W_hh, b_ih, b_hh, embed, blockmax,
                               hin, hout, c, chars_out, t);
            hipLaunchKernelGGL(k_head_fb, dim3(NBH), dim3(256), 0, stream,
                               W_head, b_head, hout,
                               logits_out + (size_t)t * NC, blockmax);
        }
        hipLaunchKernelGGL(k_final_fb, dim3(1), dim3(256), 0, stream, blockmax, chars_out);
    }
}